// Round 9
// baseline (51691.357 us; speedup 1.0000x reference)
//
#include <hip/hip_runtime.h>
#include <hip/hip_bf16.h>
#include <math.h>

#define BB 256
#define TT 256
#define INW 256
#define HH 1024
#define LL 8
#define CSW 10
#define OUTW 64
#define GG 4112
#define KXP 896            // x-part GEMM K: 3*288 = 864 padded
#define NPAD 4224          // 4112 padded to 33*128
#define BH2 (BB * 2048)    // h ring slot stride: [b][0..1023]=hi, [1024..2047]=lo
#define NBLK 256
// flag regions (u32 indices), sized for TCH<=16
#define REL_OFF 4096
#define HFL_OFF 5120
#define FLAGS_U32 7168

typedef __attribute__((ext_vector_type(8))) short short8;
typedef __attribute__((ext_vector_type(4))) float f32x4;

__device__ __forceinline__ float bf2f(ushort u) {
    union { float f; unsigned int i; } v; v.i = ((unsigned int)u) << 16; return v.f;
}
__device__ __forceinline__ ushort f2bf(float f) {
    __hip_bfloat16 h = __float2bfloat16(f);
    return *(ushort*)&h;
}
__device__ __forceinline__ float sigf(float v) { return 1.0f / (1.0f + expf(-v)); }

// ---- IF-visible write-through stores ----
__device__ __forceinline__ void st_wt_f32x4(float* p, f32x4 v) {
    asm volatile("global_store_dwordx4 %0, %1, off sc0 sc1" :: "v"(p), "v"(v) : "memory");
}
__device__ __forceinline__ void st_wt_u32(unsigned int* p, unsigned int v) {
    asm volatile("global_store_dword %0, %1, off sc0 sc1" :: "v"(p), "v"(v) : "memory");
}
__device__ __forceinline__ unsigned int ld_flag(unsigned int* p) {
    return __hip_atomic_load(p, __ATOMIC_RELAXED, __HIP_MEMORY_SCOPE_AGENT);
}

// ================= persistent scan kernel v3 (flag barriers) =================
// 256 blocks x 512 threads. Block: xcd=bid&7, jj=bid>>3; mt=xcd>>2 (group), nt=(xcd&3)*32+jj.
// Owns gate cols pc0=nt*32 (units nt*8..+7), W in LDS, c in registers.
// Helpers (jj==0): compute 16 softmax cols for rows hid*32..+31, publish fm/im + hflag.
// Sync: per-step ONE group barrier (arrive flags -> checker -> release); fm/im via hflags.
__global__ __launch_bounds__(512) void scan_kernel(
    const ushort* __restrict__ WhiP, const ushort* __restrict__ WloP,
    const ushort* __restrict__ WspT, ushort* __restrict__ hR,
    float* __restrict__ cSt, const float* __restrict__ xoX,
    const float* __restrict__ bcp, float* __restrict__ fmAll,
    float* __restrict__ dist, unsigned int* __restrict__ flags,
    int tBase, int TCH, int RING)
{
    __shared__ ushort Wh_s[32 * 1032];      // 66048 B
    __shared__ ushort Wl_s[32 * 1032];      // 66048 B
    __shared__ ushort AhAl_s[2 * 128 * 36]; // 18432 B, aliased as xo f32 after K-loop
    __shared__ ushort Wsp_s[32 * 72];       // 4608 B, aliased as sp f32 after K-loop
    __shared__ ushort hOut_s[128 * 8];      // 2048 B
    __shared__ ushort loOut_s[128 * 8];     // 2048 B
    __shared__ float bc_s[32];

    ushort* Ah_s = AhAl_s;
    ushort* Al_s = AhAl_s + 128 * 36;

    const int tid = threadIdx.x, lane = tid & 63, wave = tid >> 6;
    const int bid = blockIdx.x;
    const int xcd = bid & 7, jj = bid >> 3;
    const int mt = xcd >> 2;              // group
    const int nt = (xcd & 3) * 32 + jj;   // 0..127
    const int m0 = mt * 128;
    const int pc0 = nt * 32;
    const bool isHelper = (jj == 0);
    const int hid = xcd;
    const int mid = jj * 4 + (xcd & 3);   // member id within group [0,128)
    const bool isChk = (bid == 8 + 4 * mt);
    const int wr = wave >> 1, wc = wave & 1;

    // ---- load W slice to LDS (once) ----
    for (int i = tid; i < 32 * 128; i += 512) {
        int col = i >> 7, k8 = (i & 127) * 8;
        *(short8*)(Wh_s + col * 1032 + k8) = *(const short8*)(WhiP + (size_t)(pc0 + col) * 1024 + k8);
        *(short8*)(Wl_s + col * 1032 + k8) = *(const short8*)(WloP + (size_t)(pc0 + col) * 1024 + k8);
    }
    if (tid < 32) bc_s[tid] = bcp[pc0 + tid];

    const int rloc = tid >> 3, uu = tid & 7;
    const int grow = m0 + rloc;
    const int e = nt * 8 + uu;
    const int ll = e >> 7;
    float cReg0 = cSt[(size_t)grow * HH + e];
    float cReg1 = cSt[(size_t)(grow + 64) * HH + e];
    __syncthreads();

    const int arow = tid >> 2, ak8 = (tid & 3) * 8;
    const int spHalf = tid >> 6, spRow = (tid >> 2) & 15, spK8 = (tid & 3) * 8; // tid<128

    for (int tt = 0; tt < TCH; ++tt) {
        const int t = tBase + tt;
        const ushort* hA = hR + (size_t)((t + 8) % RING) * BH2 + (size_t)m0 * 2048;
        // 6 independent accumulators (break MFMA dep chains)
        f32x4 aHH0 = {}, aHL0 = {}, aLH0 = {}, aHH1 = {}, aHL1 = {}, aLH1 = {};
        f32x4 sHH = {}, sHL = {}, sLH = {};
        short8 pH[2], pL[2], pS[2];
        pH[0] = *(const short8*)(hA + (size_t)arow * 2048 + ak8);
        pL[0] = *(const short8*)(hA + (size_t)arow * 2048 + 1024 + ak8);
        pH[1] = *(const short8*)(hA + (size_t)arow * 2048 + 32 + ak8);
        pL[1] = *(const short8*)(hA + (size_t)arow * 2048 + 1024 + 32 + ak8);
        if (isHelper && tid < 128) {
            pS[0] = *(const short8*)(WspT + (size_t)(spHalf * 16 + spRow) * 1024 + spK8);
            pS[1] = *(const short8*)(WspT + (size_t)(spHalf * 16 + spRow) * 1024 + 32 + spK8);
        }

        for (int it = 0; it < 32; ++it) {
            const int sel = it & 1;
            *(short8*)(Ah_s + arow * 36 + ak8) = pH[sel];
            *(short8*)(Al_s + arow * 36 + ak8) = pL[sel];
            if (isHelper && tid < 128)
                *(short8*)(Wsp_s + (spHalf * 16 + spRow) * 72 + spK8) = pS[sel];
            __syncthreads();
            if (it + 2 < 32) {
                int kn = (it + 2) * 32;
                pH[sel] = *(const short8*)(hA + (size_t)arow * 2048 + kn + ak8);
                pL[sel] = *(const short8*)(hA + (size_t)arow * 2048 + 1024 + kn + ak8);
                if (isHelper && tid < 128)
                    pS[sel] = *(const short8*)(WspT + (size_t)(spHalf * 16 + spRow) * 1024 + kn + spK8);
            }
            const int fr = lane & 15, fk = (lane >> 4) * 8;
            short8 bH = *(const short8*)(Wh_s + (wc * 16 + fr) * 1032 + it * 32 + fk);
            short8 bL = *(const short8*)(Wl_s + (wc * 16 + fr) * 1032 + it * 32 + fk);
            short8 aH0 = *(const short8*)(Ah_s + (wr * 32 + fr) * 36 + fk);
            short8 aL0 = *(const short8*)(Al_s + (wr * 32 + fr) * 36 + fk);
            short8 aH1 = *(const short8*)(Ah_s + (wr * 32 + 16 + fr) * 36 + fk);
            short8 aL1 = *(const short8*)(Al_s + (wr * 32 + 16 + fr) * 36 + fk);
            aHH0 = __builtin_amdgcn_mfma_f32_16x16x32_bf16(aH0, bH, aHH0, 0, 0, 0);
            aHH1 = __builtin_amdgcn_mfma_f32_16x16x32_bf16(aH1, bH, aHH1, 0, 0, 0);
            aHL0 = __builtin_amdgcn_mfma_f32_16x16x32_bf16(aH0, bL, aHL0, 0, 0, 0);
            aHL1 = __builtin_amdgcn_mfma_f32_16x16x32_bf16(aH1, bL, aHL1, 0, 0, 0);
            aLH0 = __builtin_amdgcn_mfma_f32_16x16x32_bf16(aL0, bH, aLH0, 0, 0, 0);
            aLH1 = __builtin_amdgcn_mfma_f32_16x16x32_bf16(aL1, bH, aLH1, 0, 0, 0);
            if (isHelper && wave < 2) {
                int srl = (hid & 3) * 32 + wave * 16;
                short8 sH = *(const short8*)(Ah_s + (srl + fr) * 36 + fk);
                short8 sL = *(const short8*)(Al_s + (srl + fr) * 36 + fk);
                short8 wH = *(const short8*)(Wsp_s + fr * 72 + fk);
                short8 wL = *(const short8*)(Wsp_s + (16 + fr) * 72 + fk);
                sHH = __builtin_amdgcn_mfma_f32_16x16x32_bf16(sH, wH, sHH, 0, 0, 0);
                sHL = __builtin_amdgcn_mfma_f32_16x16x32_bf16(sH, wL, sHL, 0, 0, 0);
                sLH = __builtin_amdgcn_mfma_f32_16x16x32_bf16(sL, wH, sLH, 0, 0, 0);
            }
            __syncthreads();
        }
        // ---- xo -> LDS (alias A), sp -> LDS (alias Wsp) ----
        float* xo_s = (float*)AhAl_s;   // [128][36]
        float* sp_s = (float*)Wsp_s;    // [32][20]
        f32x4 acc0 = aHH0 + aHL0 + aLH0;
        f32x4 acc1 = aHH1 + aHL1 + aLH1;
#pragma unroll
        for (int j = 0; j < 4; ++j) {
            int r0 = wr * 32 + ((lane >> 4) << 2) + j;
            int col = wc * 16 + (lane & 15);
            xo_s[r0 * 36 + col] = acc0[j];
            xo_s[(r0 + 16) * 36 + col] = acc1[j];
        }
        if (isHelper && wave < 2) {
            f32x4 asp = sHH + sHL + sLH;
#pragma unroll
            for (int j = 0; j < 4; ++j) {
                int srow = wave * 16 + ((lane >> 4) << 2) + j;
                sp_s[srow * 20 + (lane & 15)] = asp[j];
            }
        }
        __syncthreads();
        // ---- helpers: softmax -> fm/im (write-through) + dist, publish hflag ----
        if (isHelper) {
            if (tid < 32) {
                int r = tid, growS = hid * 32 + r;
                const float* xxs = xoX + ((size_t)tt * 256 + growS) * NPAD + 4096;
                float xr[16];
#pragma unroll
                for (int q = 0; q < 16; ++q) xr[q] = sp_s[r * 20 + q] + xxs[q] + bcp[4096 + q];
                float m1 = -1e30f, m2 = -1e30f;
                for (int q = 0; q < 8; ++q) { m1 = fmaxf(m1, xr[q]); m2 = fmaxf(m2, xr[8 + q]); }
                float e1[8], e2[8], s1 = 0.f, s2 = 0.f;
                for (int q = 0; q < 8; ++q) {
                    e1[q] = expf(xr[q] - m1); s1 += e1[q];
                    e2[q] = expf(xr[8 + q] - m2); s2 += e2[q];
                }
                float cum = 0.f, mean = 0.f, fmv[8], imv[8];
                for (int q = 0; q < 8; ++q) { cum += e1[q] / s1; fmv[q] = cum; mean += cum; }
                float rc = 0.f;
                for (int q = 7; q >= 0; --q) { rc += e2[q] / s2; imv[q] = rc; }
                float* fp = fmAll + ((size_t)tt * 256 + growS) * 16;
                f32x4 v0 = {fmv[0], fmv[1], fmv[2], fmv[3]}, v1 = {fmv[4], fmv[5], fmv[6], fmv[7]};
                f32x4 v2 = {imv[0], imv[1], imv[2], imv[3]}, v3 = {imv[4], imv[5], imv[6], imv[7]};
                st_wt_f32x4(fp, v0); st_wt_f32x4(fp + 4, v1);
                st_wt_f32x4(fp + 8, v2); st_wt_f32x4(fp + 12, v3);
                dist[(size_t)t * BB + growS] = 1.0f - mean * 0.125f;
                asm volatile("s_waitcnt vmcnt(0)" ::: "memory");
            }
            __syncthreads();
            if (tid == 0) st_wt_u32(flags + HFL_OFF + ((size_t)tt * 8 + hid) * 16, 1u);
        }
        // ---- phase S prep: issue xv loads, then wait for the 4 helper flags ----
        const float* xxg0 = xoX + ((size_t)tt * 256 + grow) * NPAD + e * 4;
        const float* xxg1 = xoX + ((size_t)tt * 256 + grow + 64) * NPAD + e * 4;
        f32x4 xv0 = *(const f32x4*)xxg0;
        f32x4 xv1 = *(const f32x4*)xxg1;
        if (tid < 4) {
            unsigned int* fp = flags + HFL_OFF + ((size_t)tt * 8 + mt * 4 + tid) * 16;
            while (ld_flag(fp) == 0) __builtin_amdgcn_s_sleep(1);
        }
        __syncthreads();
        // ---- phase S: gates + cell update (c in registers), pack h via LDS ----
        {
            float bc0 = bc_s[uu * 4 + 0], bc1 = bc_s[uu * 4 + 1];
            float bc2 = bc_s[uu * 4 + 2], bc3 = bc_s[uu * 4 + 3];
            {
                f32x4 g = *(const f32x4*)(xo_s + rloc * 36 + uu * 4);
                float fmv = fmAll[((size_t)tt * 256 + grow) * 16 + ll];
                float imv = fmAll[((size_t)tt * 256 + grow) * 16 + 8 + ll];
                float f = sigf(g[0] + xv0[0] + bc0);
                float ig = sigf(g[1] + xv0[1] + bc1);
                float og = sigf(g[2] + xv0[2] + bc2);
                float ci = tanhf(g[3] + xv0[3] + bc3);
                float OV = fmv * imv;
                float cn = OV * (f * cReg0 + ig * ci) + (fmv - OV) * cReg0 + (imv - OV) * ci;
                float hn = og * tanhf(cn);
                cReg0 = cn;
                ushort hi = f2bf(hn);
                hOut_s[rloc * 8 + uu] = hi;
                loOut_s[rloc * 8 + uu] = f2bf(hn - bf2f(hi));
            }
            {
                f32x4 g = *(const f32x4*)(xo_s + (rloc + 64) * 36 + uu * 4);
                float fmv = fmAll[((size_t)tt * 256 + grow + 64) * 16 + ll];
                float imv = fmAll[((size_t)tt * 256 + grow + 64) * 16 + 8 + ll];
                float f = sigf(g[0] + xv1[0] + bc0);
                float ig = sigf(g[1] + xv1[1] + bc1);
                float og = sigf(g[2] + xv1[2] + bc2);
                float ci = tanhf(g[3] + xv1[3] + bc3);
                float OV = fmv * imv;
                float cn = OV * (f * cReg1 + ig * ci) + (fmv - OV) * cReg1 + (imv - OV) * ci;
                float hn = og * tanhf(cn);
                cReg1 = cn;
                ushort hi = f2bf(hn);
                hOut_s[(rloc + 64) * 8 + uu] = hi;
                loOut_s[(rloc + 64) * 8 + uu] = f2bf(hn - bf2f(hi));
            }
        }
        __syncthreads();
        {
            int slot = (t + 9) % RING;
            if (tid < 128) {
                ushort* hp = hR + (size_t)slot * BH2 + (size_t)(m0 + tid) * 2048 + nt * 8;
                st_wt_f32x4((float*)hp, *(f32x4*)(hOut_s + tid * 8));
            } else if (tid < 256) {
                int row = tid - 128;
                ushort* hp = hR + (size_t)slot * BH2 + (size_t)(m0 + row) * 2048 + 1024 + nt * 8;
                st_wt_f32x4((float*)hp, *(f32x4*)(loOut_s + row * 8));
            }
        }
        // ---- group barrier: arrive -> checker -> release ----
        asm volatile("s_waitcnt vmcnt(0)" ::: "memory");
        __syncthreads();
        if (tid == 0) st_wt_u32(flags + ((size_t)mt * TCH + tt) * 128 + mid, 1u);
        if (isChk) {
            if (tid < 128) {
                unsigned int* fp = flags + ((size_t)mt * TCH + tt) * 128 + tid;
                while (ld_flag(fp) == 0) __builtin_amdgcn_s_sleep(1);
            }
            __syncthreads();
            if (tid == 0) st_wt_u32(flags + REL_OFF + ((size_t)mt * TCH + tt) * 32, 1u);
        }
        if (tid == 0) {
            unsigned int* fp = flags + REL_OFF + ((size_t)mt * TCH + tt) * 32;
            while (ld_flag(fp) == 0) __builtin_amdgcn_s_sleep(1);
        }
        __syncthreads();
    }
    cSt[(size_t)grow * HH + e] = cReg0;
    cSt[(size_t)(grow + 64) * HH + e] = cReg1;
}

// ================= generic bf16 MFMA GEMM (x-part + phase 2) =================
template<int WR, int WC, int AMODE, int EPI>
__global__ __launch_bounds__(WR * WC * 64) void mm_kernel(
    const ushort* __restrict__ A, const ushort* __restrict__ hR,
    const ushort* __restrict__ BT, const float* __restrict__ bias,
    void* __restrict__ Cp, const float* __restrict__ ldw,
    const ushort* __restrict__ TH, float* __restrict__ outp,
    int ldaA, int ldb, int ldc, int K, int t, int RING, int tBase)
{
    constexpr int BM = WR * 64, BN = WC * 64, NT = WR * WC * 64, LS = 72;
    constexpr int AIT = BM * 8 / NT, BIT = BN * 8 / NT;
    __shared__ ushort As[BM * LS];
    __shared__ ushort Bs[BN * LS];
    const int tid = threadIdx.x;
    const int lane = tid & 63, wave = tid >> 6;
    const int wr = wave / WC, wc = wave % WC;

    int bx, by;
    if (AMODE == 2) {
        int vid = blockIdx.x;
        bx = (vid >> 3) & 7;
        by = ((vid >> 6) << 3) + (vid & 7);
        if (by >= t) return;        // t carries nM
    } else {
        bx = blockIdx.x; by = blockIdx.y;
    }
    const int m0 = by * BM, n0 = bx * BN;
    f32x4 acc[4][4] = {};

    auto gather = [&](int ktl, short8* vA, short8* vB) {
#pragma unroll
        for (int i = 0; i < AIT; ++i) {
            int id = tid + i * NT;
            int r = id >> 3, cc = id & 7;
            int k = ktl + cc * 8;
            short8 v;
            if (AMODE == 0) {
                v = *(const short8*)(A + (size_t)(m0 + r) * ldaA + k);
            } else {  // conv gather
                int ks = k >> 10, c = k & 1023;
                int tt = m0 >> 8, b = (m0 & 255) + r;
                int slot = (tBase + tt + ks) % RING;
                short8 hv = *(const short8*)(hR + (size_t)slot * BH2 + (size_t)b * 2048 + c);
                float s = ldw[((size_t)tt * 256 + b) * CSW + ks];
                ushort* pv = (ushort*)&hv;
                ushort* po = (ushort*)&v;
#pragma unroll
                for (int j = 0; j < 8; ++j) po[j] = f2bf(bf2f(pv[j]) * s);
            }
            vA[i] = v;
        }
#pragma unroll
        for (int i = 0; i < BIT; ++i) {
            int id = tid + i * NT;
            int n = id >> 3, cc = id & 7;
            vB[i] = *(const short8*)(BT + (size_t)(n0 + n) * ldb + ktl + cc * 8);
        }
    };

    short8 vA[AIT], vB[BIT];
    gather(0, vA, vB);

    for (int kt = 0; kt < K; kt += 64) {
#pragma unroll
        for (int i = 0; i < AIT; ++i) {
            int id = tid + i * NT;
            *(short8*)(As + (id >> 3) * LS + (id & 7) * 8) = vA[i];
        }
#pragma unroll
        for (int i = 0; i < BIT; ++i) {
            int id = tid + i * NT;
            *(short8*)(Bs + (id >> 3) * LS + (id & 7) * 8) = vB[i];
        }
        __syncthreads();
        if (kt + 64 < K) gather(kt + 64, vA, vB);
#pragma unroll
        for (int kf = 0; kf < 2; ++kf) {
            short8 aF[4], bF[4];
#pragma unroll
            for (int mi = 0; mi < 4; ++mi)
                aF[mi] = *(const short8*)(As + (wr * 64 + mi * 16 + (lane & 15)) * LS + kf * 32 + (lane >> 4) * 8);
#pragma unroll
            for (int ni = 0; ni < 4; ++ni)
                bF[ni] = *(const short8*)(Bs + (wc * 64 + ni * 16 + (lane & 15)) * LS + kf * 32 + (lane >> 4) * 8);
#pragma unroll
            for (int mi = 0; mi < 4; ++mi)
#pragma unroll
                for (int ni = 0; ni < 4; ++ni)
                    acc[mi][ni] = __builtin_amdgcn_mfma_f32_16x16x32_bf16(aF[mi], bF[ni], acc[mi][ni], 0, 0, 0);
        }
        __syncthreads();
    }
#pragma unroll
    for (int mi = 0; mi < 4; ++mi) {
#pragma unroll
        for (int ni = 0; ni < 4; ++ni) {
#pragma unroll
            for (int j = 0; j < 4; ++j) {
                int row = m0 + wr * 64 + mi * 16 + ((lane >> 4) << 2) + j;
                int col = n0 + wc * 64 + ni * 16 + (lane & 15);
                float v = acc[mi][ni][j];
                if (EPI != 0 && bias) v += bias[col];
                if (EPI == 0) {
                    ((float*)Cp)[(size_t)row * ldc + col] = v;
                } else if (EPI == 1) {
                    ((ushort*)Cp)[(size_t)row * ldc + col] = f2bf(v > 0.f ? v : 0.f);
                } else if (EPI == 2) {
                    ((ushort*)Cp)[(size_t)row * ldc + col] = f2bf(sigf(v));
                } else if (EPI == 3) {
                    int tt = row >> 8, b = row & 255;
                    int slot = (tBase + tt + 9) % RING;
                    float th = bf2f(TH[(size_t)row * HH + col]);
                    float h = bf2f(hR[(size_t)slot * BH2 + (size_t)b * 2048 + col]);
                    ((ushort*)Cp)[(size_t)row * ldc + col] = f2bf(th * v + h);
                } else {
                    int tt = tBase + (row >> 8), b = row & 255;
                    outp[((size_t)b * TT + tt) * OUTW + col] = sigf(v);
                }
            }
        }
    }
}

// ================= weight / input prep =================
__device__ __forceinline__ int pcol_to_orig(int n) {
    if (n < 4096) return 16 + (n & 3) * 1024 + (n >> 2);
    if (n < 4112) return n - 4096;
    return -1;
}

__global__ void build_whlP(const float* __restrict__ rw,
                           ushort* __restrict__ WhiP, ushort* __restrict__ WloP)
{
    size_t i = (size_t)blockIdx.x * 256 + threadIdx.x;
    if (i >= (size_t)4096 * 1024) return;
    int pc = (int)(i >> 10), k = (int)(i & 1023);
    int n = 16 + (pc & 3) * 1024 + (pc >> 2);
    float w = rw[(size_t)k * GG + n];
    ushort hi = f2bf(w);
    WhiP[i] = hi;
    WloP[i] = f2bf(w - bf2f(hi));
}

__global__ void build_wsp(const float* __restrict__ rw, ushort* __restrict__ WspT)
{
    int i = blockIdx.x * 256 + threadIdx.x;
    if (i >= 16 * 1024) return;
    int r = i >> 10, k = i & 1023;
    float w = rw[(size_t)k * GG + r];
    ushort hi = f2bf(w);
    WspT[i] = hi;
    WspT[16 * 1024 + i] = f2bf(w - bf2f(hi));
}

__global__ void build_wxt(const float* __restrict__ kw, const float* __restrict__ rw,
                          ushort* __restrict__ WxT)
{
    size_t i = (size_t)blockIdx.x * 256 + threadIdx.x;
    if (i >= (size_t)NPAD * KXP) return;
    int n = (int)(i / KXP), k = (int)(i % KXP);
    int seg = k / 288, kk = k - seg * 288;
    int oc = pcol_to_orig(n);
    float w = 0.f;
    if (oc >= 0 && seg < 3) {
        if (kk < 256)       w = kw[(size_t)kk * GG + oc];
        else if (kk == 256) w = kw[(size_t)256 * GG + oc];
        else if (kk == 257) w = rw[(size_t)1024 * GG + oc];
    }
    ushort hi = f2bf(w);
    WxT[i] = (seg == 1) ? f2bf(w - bf2f(hi)) : hi;
}

__global__ void build_bcp(const float* __restrict__ kb, const float* __restrict__ rb,
                          float* __restrict__ bcp)
{
    int i = blockIdx.x * 256 + threadIdx.x;
    if (i >= NPAD) return;
    int oc = pcol_to_orig(i);
    bcp[i] = (oc >= 0) ? kb[oc] + rb[oc] : 0.f;
}

__global__ void build_xac(const float* __restrict__ x, const float* __restrict__ tim,
                          ushort* __restrict__ XAc, int tBase, int Mloc)
{
    size_t i = (size_t)blockIdx.x * 256 + threadIdx.x;
    if (i >= (size_t)Mloc * KXP) return;
    int m = (int)(i / KXP), k = (int)(i % KXP);
    int t = tBase + (m >> 8), b = m & 255;
    int seg = k / 288, kk = k - seg * 288;
    float v = 0.f;
    if (seg < 3) {
        if (kk < 256)      v = x[((size_t)b * TT + t) * INW + kk];
        else if (kk < 258) v = tim[(size_t)b * TT + t];
    }
    ushort hi = f2bf(v);
    XAc[i] = (seg == 2) ? f2bf(v - bf2f(hi)) : hi;
}

__global__ void build_ctt(const float* __restrict__ cw, ushort* __restrict__ ctT)
{
    size_t i = (size_t)blockIdx.x * 256 + threadIdx.x;
    if (i >= (size_t)HH * HH * CSW) return;
    int o = (int)(i / (HH * CSW)), rest = (int)(i % (HH * CSW));
    int k = rest >> 10, c = rest & 1023;
    ctT[i] = f2bf(cw[((size_t)o * HH + c) * CSW + k]);
}

__global__ void build_swt(const float* __restrict__ sw, const float* __restrict__ sb,
                          ushort* __restrict__ swT, float* __restrict__ sbP)
{
    int i = blockIdx.x * 256 + threadIdx.x;
    if (i < 256 * 1024) {
        int n = i >> 10, k = i & 1023;
        swT[i] = f2bf(n < 170 ? sw[(size_t)k * 170 + n] : 0.f);
    }
    if (i < 256) sbP[i] = (i < 170) ? sb[i] : 0.f;
}

__global__ void build_rswt(const float* __restrict__ rsw, ushort* __restrict__ rswT)
{
    int i = blockIdx.x * 256 + threadIdx.x;
    if (i >= 1024 * 256) return;
    int n = i >> 8, k = i & 255;
    rswT[i] = f2bf(k < 170 ? rsw[(size_t)k * HH + n] : 0.f);
}

__global__ void build_owt(const float* __restrict__ ow, ushort* __restrict__ owT)
{
    int i = blockIdx.x * 256 + threadIdx.x;
    if (i >= OUTW * HH) return;
    int n = i >> 10, k = i & 1023;
    owT[i] = f2bf(ow[(size_t)k * OUTW + n]);
}

// ================= chunk helpers =================
__global__ void ld_chunk_kernel(const float* __restrict__ dist, float* __restrict__ ldC,
                                int tBase, int Mloc)
{
    int id = blockIdx.x * 256 + threadIdx.x;
    if (id >= Mloc) return;
    int t = tBase + (id >> 8), b = id & 255;
    float cv[CSW], cum = 0.f, mx = -1e30f;
#pragma unroll
    for (int k = 0; k < CSW; ++k) {
        int ts = t - 9 + k;
        cum += (ts >= 0) ? dist[(size_t)ts * BB + b] : 0.f;
        cv[k] = cum; mx = fmaxf(mx, cum);
    }
    float ss = 0.f;
#pragma unroll
    for (int k = 0; k < CSW; ++k) { cv[k] = expf(cv[k] - mx); ss += cv[k]; }
    float inv = 1.0f / ss;
#pragma unroll
    for (int k = 0; k < CSW; ++k) ldC[(size_t)id * CSW + k] = cv[k] * inv;
}

__global__ void mlh_kernel(const ushort* __restrict__ hR, const float* __restrict__ ldC,
                           ushort* __restrict__ MLH, int tBase, int RING)
{
    size_t id = (size_t)blockIdx.x * 256 + threadIdx.x;
    int m = (int)(id >> 7);
    int c0 = ((int)(id & 127)) << 3;
    int t = tBase + (m >> 8), b = m & 255;
    float acc[8] = {};
#pragma unroll
    for (int k = 0; k < CSW; ++k) {
        float s = ldC[(size_t)m * CSW + k];
        int slot = (t + k) % RING;
        short8 hv = *(const short8*)(hR + (size_t)slot * BH2 + (size_t)b * 2048 + c0);
        ushort* pv = (ushort*)&hv;
#pragma unroll
        for (int j = 0; j < 8; ++j) acc[j] += bf2f(pv[j]) * s;
    }
#pragma unroll
    for (int j = 0; j < 8; ++j) MLH[(size_t)m * HH + c0 + j] = f2bf(acc[j] * 0.1f);
}

// ================= launch =================
extern "C" void kernel_launch(void* const* d_in, const int* in_sizes, int n_in,
                              void* d_out, int out_size, void* d_ws, size_t ws_size,
                              hipStream_t stream)
{
    const float* x   = (const float*)d_in[0];
    const float* tim = (const float*)d_in[1];
    const float* kw  = (const float*)d_in[2];
    const float* kb  = (const float*)d_in[3];
    const float* rw  = (const float*)d_in[4];
    const float* rb  = (const float*)d_in[5];
    const float* sw  = (const float*)d_in[6];
    const float* sb  = (const float*)d_in[7];
    const float* rsw = (const float*)d_in[8];
    const float* rsb = (const float*)d_in[9];
    const float* cw  = (const float*)d_in[10];
    const float* cb  = (const float*)d_in[11];
    const float* ow  = (const float*)d_in[12];
    const float* ob  = (const float*)d_in[13];
    float* out  = (float*)d_out;
    float* dist = out + (size_t)BB * TT * OUTW;

    auto planSize = [&](int tch) -> size_t {
        size_t o = 0;
        auto al = [&](size_t bytes) { o += (bytes + 255) & ~(size_t)255; };
        int ring = tch + 9;
        al((size_t)ring * BH2 * 2);            // hRing (hi|lo)
        al((size_t)BB * HH * 4);               // cSt
        al((size_t)4096 * 1024 * 2);           // WhiP
        al((size_t)4096 * 1024 * 2);           // WloP
        al((size_t)32 * 1024 * 2);             // WspT
        al((size_t)NPAD * KXP * 2);            // WxT
        al((size_t)NPAD * 4);                  // bcp
        al((size_t)tch * 256 * NPAD * 4);      // xoX
        al((size_t)tch * 256 * KXP * 2);       // XAc
        al((size_t)tch * 256 * 16 * 4);        // fmAll
        al((size_t)tch * 256 * CSW * 4);       // ldC
        al((size_t)HH * HH * CSW * 2);         // ctT
        al((size_t)256 * 1024 * 2);            // swT
        al((size_t)256 * 4);                   // sbP
        al((size_t)1024 * 256 * 2);            // rswT
        al((size_t)OUTW * HH * 2);             // owT
        al((size_t)tch * 256 * HH * 2);        // MLH / RNN
        al((size_t)tch * 256 * 256 * 2);       // TH1
        al((size_t)tch * 256 * HH * 2);        // TH
        al((size_t)FLAGS_U32 * 4);             // flags
        return o;
    };
    const int cands[4] = {16, 8, 4, 2};
    int TCH = 0;
    for (int ci = 0; ci < 4; ++ci)
        if (planSize(cands[ci]) <= ws_size) { TCH = cands[ci]; break; }
    if (TCH == 0) return;   // diagnostic: output stays zero -> absmax ~0.83
    const int RING = TCH + 9;
    const int Mloc = TCH * 256;
    const int nM = Mloc / 128;

    char* base = (char*)d_ws;
    size_t off = 0;
    auto alloc = [&](size_t bytes) { char* p = base + off; off += (bytes + 255) & ~(size_t)255; return p; };
    ushort* hRing = (ushort*)alloc((size_t)RING * BH2 * 2);
    float*  cSt   = (float*) alloc((size_t)BB * HH * 4);
    ushort* WhiP  = (ushort*)alloc((size_t)4096 * 1024 * 2);
    ushort* WloP  = (ushort*)alloc((size_t)4096 * 1024 * 2);
    ushort* WspT  = (ushort*)alloc((size_t)32 * 1024 * 2);
    ushort* WxT   = (ushort*)alloc((size_t)NPAD * KXP * 2);
    float*  bcp   = (float*) alloc((size_t)NPAD * 4);
    float*  xoX   = (float*) alloc((size_t)Mloc * NPAD * 4);
    ushort* XAc   = (ushort*)alloc((size_t)Mloc * KXP * 2);
    float*  fmAll = (float*) alloc((size_t)Mloc * 16 * 4);
    float*  ldC   = (float*) alloc((size_t)Mloc * CSW * 4);
    ushort* ctT   = (ushort*)alloc((size_t)HH * HH * CSW * 2);
    ushort* swT   = (ushort*)alloc((size_t)256 * 1024 * 2);
    float*  sbP   = (float*) alloc((size_t)256 * 4);
    ushort* rswT  = (ushort*)alloc((size_t)1024 * 256 * 2);
    ushort* owT   = (ushort*)alloc((size_t)OUTW * HH * 2);
    ushort* MLH   = (ushort*)alloc((size_t)Mloc * HH * 2);
    ushort* TH1   = (ushort*)alloc((size_t)Mloc * 256 * 2);
    ushort* TH    = (ushort*)alloc((size_t)Mloc * HH * 2);
    unsigned int* flags = (unsigned int*)alloc((size_t)FLAGS_U32 * 4);
    ushort* RNN   = MLH;

    hipMemsetAsync(hRing, 0, (size_t)9 * BH2 * 2, stream);
    hipMemsetAsync(cSt, 0, (size_t)BB * HH * 4, stream);

    build_whlP<<<(int)(((size_t)4096 * 1024 + 255) / 256), 256, 0, stream>>>(rw, WhiP, WloP);
    build_wsp<<<(16 * 1024 + 255) / 256, 256, 0, stream>>>(rw, WspT);
    build_wxt<<<(int)(((size_t)NPAD * KXP + 255) / 256), 256, 0, stream>>>(kw, rw, WxT);
    build_bcp<<<(NPAD + 255) / 256, 256, 0, stream>>>(kb, rb, bcp);
    build_ctt<<<(int)(((size_t)HH * HH * CSW + 255) / 256), 256, 0, stream>>>(cw, ctT);
    build_swt<<<(256 * 1024 + 255) / 256, 256, 0, stream>>>(sw, sb, swT, sbP);
    build_rswt<<<(1024 * 256 + 255) / 256, 256, 0, stream>>>(rsw, rswT);
    build_owt<<<(OUTW * HH + 255) / 256, 256, 0, stream>>>(ow, owT);

    for (int tBase = 0; tBase < TT; tBase += TCH) {
        // ---- batched x-part: xoX = XAc @ WxT (permuted N) ----
        build_xac<<<(int)(((size_t)Mloc * KXP + 255) / 256), 256, 0, stream>>>(
            x, tim, XAc, tBase, Mloc);
        mm_kernel<2, 2, 0, 0><<<dim3(33, Mloc / 128), 256, 0, stream>>>(
            XAc, nullptr, WxT, nullptr, xoX, nullptr, nullptr, nullptr,
            KXP, KXP, NPAD, KXP, 0, RING, tBase);
        // ---- persistent scan (flag barriers) ----
        hipMemsetAsync(flags, 0, (size_t)FLAGS_U32 * 4, stream);
        scan_kernel<<<NBLK, 512, 0, stream>>>(
            WhiP, WloP, WspT, hRing, cSt, xoX, bcp, fmAll, dist, flags,
            tBase, TCH, RING);
        // ---- batched phase-2 ----
        ld_chunk_kernel<<<(Mloc + 255) / 256, 256, 0, stream>>>(dist, ldC, tBase, Mloc);
        mlh_kernel<<<Mloc / 2, 256, 0, stream>>>(hRing, ldC, MLH, tBase, RING);
        mm_kernel<2, 2, 0, 1><<<dim3(2, Mloc / 128), 256, 0, stream>>>(
            MLH, nullptr, swT, sbP, TH1, nullptr, nullptr, nullptr,
            1024, 1024, 256, 1024, 0, RING, tBase);
        mm_kernel<2, 2, 0, 2><<<dim3(8, Mloc / 128), 256, 0, stream>>>(
            TH1, nullptr, rswT, rsb, TH, nullptr, nullptr, nullptr,
            256, 256, 1024, 256, 0, RING, tBase);
        mm_kernel<2, 2, 2, 3><<<dim3(((nM + 7) / 8) * 64), 256, 0, stream>>>(
            nullptr, hRing, ctT, cb, RNN, ldC, TH, nullptr,
            0, HH * CSW, 1024, HH * CSW, nM, RING, tBase);
        mm_kernel<4, 1, 0, 4><<<dim3(1, Mloc / 256), 256, 0, stream>>>(
            RNN, nullptr, owT, ob, nullptr, nullptr, nullptr, out,
            1024, 1024, 0, 1024, 0, RING, tBase);
    }
}

// Round 10
// 21400.909 us; speedup vs baseline: 2.4154x; 2.4154x over previous
//
#include <hip/hip_runtime.h>
#include <hip/hip_bf16.h>
#include <math.h>

#define BB 256
#define TT 256
#define INW 256
#define HH 1024
#define LL 8
#define CSW 10
#define OUTW 64
#define GG 4112
#define KXP 896            // x-part GEMM K: 3*288 = 864 padded
#define NPAD 4224          // 4112 padded to 33*128
#define BH2 (BB * 2048)    // h ring slot stride: [b][0..1023]=hi, [1024..2047]=lo
#define NBLK 256
// flags: per (global t, group mt): 64 slots x 16 u32 (64B) each.
//   slot 0..15  = L1 arrive counters (8 blocks each)
//   slot 16     = L2 group counter (16 bumps)
//   slot 17..32 = release lines (fan-out)
//   slot 33..48 = hCnt fan-out lines (4 helper bumps each)
#define FLAGS_U32 ((size_t)TT * 2 * 64 * 16)

typedef __attribute__((ext_vector_type(8))) short short8;
typedef __attribute__((ext_vector_type(4))) float f32x4;

__device__ __forceinline__ float bf2f(ushort u) {
    union { float f; unsigned int i; } v; v.i = ((unsigned int)u) << 16; return v.f;
}
__device__ __forceinline__ ushort f2bf(float f) {
    __hip_bfloat16 h = __float2bfloat16(f);
    return *(ushort*)&h;
}
__device__ __forceinline__ float sigf(float v) { return 1.0f / (1.0f + expf(-v)); }

// ---- IF-visible write-through stores ----
__device__ __forceinline__ void st_wt_f32x4(float* p, f32x4 v) {
    asm volatile("global_store_dwordx4 %0, %1, off sc0 sc1" :: "v"(p), "v"(v) : "memory");
}
// ---- coherent RMW helpers (execute at LLC; no stale-L2 ambiguity) ----
__device__ __forceinline__ unsigned int rmw_add(unsigned int* p, unsigned int v) {
    return __hip_atomic_fetch_add(p, v, __ATOMIC_RELAXED, __HIP_MEMORY_SCOPE_AGENT);
}
__device__ __forceinline__ unsigned int rmw_read(unsigned int* p) {
    return __hip_atomic_fetch_add(p, 0u, __ATOMIC_RELAXED, __HIP_MEMORY_SCOPE_AGENT);
}

// ================= persistent scan kernel v4 (RMW-only sync) =================
// 256 blocks x 512 threads. Block: xcd=bid&7, jj=bid>>3; mt=xcd>>2 (group), nt=(xcd&3)*32+jj.
// Owns gate cols pc0=nt*32, W in LDS, c in registers.
// Helpers (jj==0): 16 softmax cols for rows hid*32..+31; publish fm/im + hCnt fan-out.
// Per step: hCnt wait (helpers->all) + ONE 3-level group barrier after h stores.
__global__ __launch_bounds__(512) void scan_kernel(
    const ushort* __restrict__ WhiP, const ushort* __restrict__ WloP,
    const ushort* __restrict__ WspT, ushort* __restrict__ hR,
    float* __restrict__ cSt, const float* __restrict__ xoX,
    const float* __restrict__ bcp, float* __restrict__ fmAll,
    float* __restrict__ dist, unsigned int* __restrict__ flags,
    int tBase, int TCH, int RING)
{
    __shared__ ushort Wh_s[32 * 1032];      // 66048 B
    __shared__ ushort Wl_s[32 * 1032];      // 66048 B
    __shared__ ushort AhAl_s[2 * 128 * 36]; // 18432 B, aliased as xo f32 after K-loop
    __shared__ ushort Wsp_s[32 * 72];       // 4608 B, aliased as sp f32 after K-loop
    __shared__ ushort hOut_s[128 * 8];      // 2048 B
    __shared__ ushort loOut_s[128 * 8];     // 2048 B
    __shared__ float bc_s[32];

    ushort* Ah_s = AhAl_s;
    ushort* Al_s = AhAl_s + 128 * 36;

    const int tid = threadIdx.x, lane = tid & 63, wave = tid >> 6;
    const int bid = blockIdx.x;
    const int xcd = bid & 7, jj = bid >> 3;
    const int mt = xcd >> 2;              // group
    const int nt = (xcd & 3) * 32 + jj;   // 0..127
    const int m0 = mt * 128;
    const int pc0 = nt * 32;
    const bool isHelper = (jj == 0);
    const int hid = xcd;
    const int mid = jj * 4 + (xcd & 3);   // member id within group [0,128)
    const int wr = wave >> 1, wc = wave & 1;

    // ---- load W slice to LDS (once) ----
    for (int i = tid; i < 32 * 128; i += 512) {
        int col = i >> 7, k8 = (i & 127) * 8;
        *(short8*)(Wh_s + col * 1032 + k8) = *(const short8*)(WhiP + (size_t)(pc0 + col) * 1024 + k8);
        *(short8*)(Wl_s + col * 1032 + k8) = *(const short8*)(WloP + (size_t)(pc0 + col) * 1024 + k8);
    }
    if (tid < 32) bc_s[tid] = bcp[pc0 + tid];

    const int rloc = tid >> 3, uu = tid & 7;
    const int grow = m0 + rloc;
    const int e = nt * 8 + uu;
    const int ll = e >> 7;
    float cReg0 = cSt[(size_t)grow * HH + e];
    float cReg1 = cSt[(size_t)(grow + 64) * HH + e];
    __syncthreads();

    const int arow = tid >> 2, ak8 = (tid & 3) * 8;
    const int spHalf = tid >> 6, spRow = (tid >> 2) & 15, spK8 = (tid & 3) * 8; // tid<128

    for (int tt = 0; tt < TCH; ++tt) {
        const int t = tBase + tt;
        unsigned int* fb = flags + ((size_t)(t * 2 + mt) * 64) * 16;  // this step+group's slots
        const ushort* hA = hR + (size_t)((t + 8) % RING) * BH2 + (size_t)m0 * 2048;
        f32x4 aHH0 = {}, aHL0 = {}, aLH0 = {}, aHH1 = {}, aHL1 = {}, aLH1 = {};
        f32x4 sHH = {}, sHL = {}, sLH = {};
        short8 pH, pL, pS = {};
        pH = *(const short8*)(hA + (size_t)arow * 2048 + ak8);
        pL = *(const short8*)(hA + (size_t)arow * 2048 + 1024 + ak8);
        if (isHelper && tid < 128)
            pS = *(const short8*)(WspT + (size_t)(spHalf * 16 + spRow) * 1024 + spK8);

        for (int it = 0; it < 32; ++it) {
            *(short8*)(Ah_s + arow * 36 + ak8) = pH;
            *(short8*)(Al_s + arow * 36 + ak8) = pL;
            if (isHelper && tid < 128)
                *(short8*)(Wsp_s + (spHalf * 16 + spRow) * 72 + spK8) = pS;
            __syncthreads();
            if (it + 1 < 32) {
                int kn = (it + 1) * 32;
                pH = *(const short8*)(hA + (size_t)arow * 2048 + kn + ak8);
                pL = *(const short8*)(hA + (size_t)arow * 2048 + 1024 + kn + ak8);
                if (isHelper && tid < 128)
                    pS = *(const short8*)(WspT + (size_t)(spHalf * 16 + spRow) * 1024 + kn + spK8);
            }
            const int fr = lane & 15, fk = (lane >> 4) * 8;
            short8 bH = *(const short8*)(Wh_s + (wc * 16 + fr) * 1032 + it * 32 + fk);
            short8 bL = *(const short8*)(Wl_s + (wc * 16 + fr) * 1032 + it * 32 + fk);
            short8 aH0 = *(const short8*)(Ah_s + (wr * 32 + fr) * 36 + fk);
            short8 aL0 = *(const short8*)(Al_s + (wr * 32 + fr) * 36 + fk);
            short8 aH1 = *(const short8*)(Ah_s + (wr * 32 + 16 + fr) * 36 + fk);
            short8 aL1 = *(const short8*)(Al_s + (wr * 32 + 16 + fr) * 36 + fk);
            aHH0 = __builtin_amdgcn_mfma_f32_16x16x32_bf16(aH0, bH, aHH0, 0, 0, 0);
            aHH1 = __builtin_amdgcn_mfma_f32_16x16x32_bf16(aH1, bH, aHH1, 0, 0, 0);
            aHL0 = __builtin_amdgcn_mfma_f32_16x16x32_bf16(aH0, bL, aHL0, 0, 0, 0);
            aHL1 = __builtin_amdgcn_mfma_f32_16x16x32_bf16(aH1, bL, aHL1, 0, 0, 0);
            aLH0 = __builtin_amdgcn_mfma_f32_16x16x32_bf16(aL0, bH, aLH0, 0, 0, 0);
            aLH1 = __builtin_amdgcn_mfma_f32_16x16x32_bf16(aL1, bH, aLH1, 0, 0, 0);
            if (isHelper && wave < 2) {
                int srl = (hid & 3) * 32 + wave * 16;
                short8 sH = *(const short8*)(Ah_s + (srl + fr) * 36 + fk);
                short8 sL = *(const short8*)(Al_s + (srl + fr) * 36 + fk);
                short8 wH = *(const short8*)(Wsp_s + fr * 72 + fk);
                short8 wL = *(const short8*)(Wsp_s + (16 + fr) * 72 + fk);
                sHH = __builtin_amdgcn_mfma_f32_16x16x32_bf16(sH, wH, sHH, 0, 0, 0);
                sHL = __builtin_amdgcn_mfma_f32_16x16x32_bf16(sH, wL, sHL, 0, 0, 0);
                sLH = __builtin_amdgcn_mfma_f32_16x16x32_bf16(sL, wH, sLH, 0, 0, 0);
            }
            __syncthreads();
        }
        // ---- xo -> LDS (alias A), sp -> LDS (alias Wsp) ----
        float* xo_s = (float*)AhAl_s;   // [128][36]
        float* sp_s = (float*)Wsp_s;    // [32][20]
        f32x4 acc0 = aHH0 + aHL0 + aLH0;
        f32x4 acc1 = aHH1 + aHL1 + aLH1;
#pragma unroll
        for (int j = 0; j < 4; ++j) {
            int r0 = wr * 32 + ((lane >> 4) << 2) + j;
            int col = wc * 16 + (lane & 15);
            xo_s[r0 * 36 + col] = acc0[j];
            xo_s[(r0 + 16) * 36 + col] = acc1[j];
        }
        if (isHelper && wave < 2) {
            f32x4 asp = sHH + sHL + sLH;
#pragma unroll
            for (int j = 0; j < 4; ++j) {
                int srow = wave * 16 + ((lane >> 4) << 2) + j;
                sp_s[srow * 20 + (lane & 15)] = asp[j];
            }
        }
        __syncthreads();
        // ---- helpers: softmax -> fm/im (write-through), then hCnt fan-out bumps ----
        if (isHelper) {
            if (tid < 32) {
                int r = tid, growS = hid * 32 + r;
                const float* xxs = xoX + ((size_t)tt * 256 + growS) * NPAD + 4096;
                float xr[16];
#pragma unroll
                for (int q = 0; q < 16; ++q) xr[q] = sp_s[r * 20 + q] + xxs[q] + bcp[4096 + q];
                float m1 = -1e30f, m2 = -1e30f;
                for (int q = 0; q < 8; ++q) { m1 = fmaxf(m1, xr[q]); m2 = fmaxf(m2, xr[8 + q]); }
                float e1[8], e2[8], s1 = 0.f, s2 = 0.f;
                for (int q = 0; q < 8; ++q) {
                    e1[q] = expf(xr[q] - m1); s1 += e1[q];
                    e2[q] = expf(xr[8 + q] - m2); s2 += e2[q];
                }
                float cum = 0.f, mean = 0.f, fmv[8], imv[8];
                for (int q = 0; q < 8; ++q) { cum += e1[q] / s1; fmv[q] = cum; mean += cum; }
                float rc = 0.f;
                for (int q = 7; q >= 0; --q) { rc += e2[q] / s2; imv[q] = rc; }
                float* fp = fmAll + ((size_t)t * 256 + growS) * 16;
                f32x4 v0 = {fmv[0], fmv[1], fmv[2], fmv[3]}, v1 = {fmv[4], fmv[5], fmv[6], fmv[7]};
                f32x4 v2 = {imv[0], imv[1], imv[2], imv[3]}, v3 = {imv[4], imv[5], imv[6], imv[7]};
                st_wt_f32x4(fp, v0); st_wt_f32x4(fp + 4, v1);
                st_wt_f32x4(fp + 8, v2); st_wt_f32x4(fp + 12, v3);
                dist[(size_t)t * BB + growS] = 1.0f - mean * 0.125f;
            }
            asm volatile("s_waitcnt vmcnt(0)" ::: "memory");  // wave 0: drain fm/im stores
            if (tid < 16) rmw_add(fb + (33 + tid) * 16, 1u);  // fan-out bump (wave 0)
        }
        // ---- consumer wait for 4 helpers (own fan-out line), xv prefetched ----
        const float* xxg0 = xoX + ((size_t)tt * 256 + grow) * NPAD + e * 4;
        const float* xxg1 = xoX + ((size_t)tt * 256 + grow + 64) * NPAD + e * 4;
        f32x4 xv0 = *(const f32x4*)xxg0;
        f32x4 xv1 = *(const f32x4*)xxg1;
        if (tid == 0) {
            unsigned int* hc = fb + (33 + (mid >> 3)) * 16;
            while (rmw_read(hc) < 4u) __builtin_amdgcn_s_sleep(2);
        }
        __syncthreads();
        // ---- phase S: gates + cell update (c in registers), pack h via LDS ----
        {
            float bc0 = bc_s[uu * 4 + 0], bc1 = bc_s[uu * 4 + 1];
            float bc2 = bc_s[uu * 4 + 2], bc3 = bc_s[uu * 4 + 3];
            {
                f32x4 g = *(const f32x4*)(xo_s + rloc * 36 + uu * 4);
                float fmv = fmAll[((size_t)t * 256 + grow) * 16 + ll];
                float imv = fmAll[((size_t)t * 256 + grow) * 16 + 8 + ll];
                float f = sigf(g[0] + xv0[0] + bc0);
                float ig = sigf(g[1] + xv0[1] + bc1);
                float og = sigf(g[2] + xv0[2] + bc2);
                float ci = tanhf(g[3] + xv0[3] + bc3);
                float OV = fmv * imv;
                float cn = OV * (f * cReg0 + ig * ci) + (fmv - OV) * cReg0 + (imv - OV) * ci;
                float hn = og * tanhf(cn);
                cReg0 = cn;
                ushort hi = f2bf(hn);
                hOut_s[rloc * 8 + uu] = hi;
                loOut_s[rloc * 8 + uu] = f2bf(hn - bf2f(hi));
            }
            {
                f32x4 g = *(const f32x4*)(xo_s + (rloc + 64) * 36 + uu * 4);
                float fmv = fmAll[((size_t)t * 256 + grow + 64) * 16 + ll];
                float imv = fmAll[((size_t)t * 256 + grow + 64) * 16 + 8 + ll];
                float f = sigf(g[0] + xv1[0] + bc0);
                float ig = sigf(g[1] + xv1[1] + bc1);
                float og = sigf(g[2] + xv1[2] + bc2);
                float ci = tanhf(g[3] + xv1[3] + bc3);
                float OV = fmv * imv;
                float cn = OV * (f * cReg1 + ig * ci) + (fmv - OV) * cReg1 + (imv - OV) * ci;
                float hn = og * tanhf(cn);
                cReg1 = cn;
                ushort hi = f2bf(hn);
                hOut_s[(rloc + 64) * 8 + uu] = hi;
                loOut_s[(rloc + 64) * 8 + uu] = f2bf(hn - bf2f(hi));
            }
        }
        __syncthreads();
        {
            int slot = (t + 9) % RING;
            if (tid < 128) {
                ushort* hp = hR + (size_t)slot * BH2 + (size_t)(m0 + tid) * 2048 + nt * 8;
                st_wt_f32x4((float*)hp, *(f32x4*)(hOut_s + tid * 8));
            } else if (tid < 256) {
                int row = tid - 128;
                ushort* hp = hR + (size_t)slot * BH2 + (size_t)(m0 + row) * 2048 + 1024 + nt * 8;
                st_wt_f32x4((float*)hp, *(f32x4*)(loOut_s + row * 8));
            }
        }
        // ---- 3-level group barrier (all RMW) ----
        asm volatile("s_waitcnt vmcnt(0)" ::: "memory");
        __syncthreads();
        if (tid == 0) {
            unsigned int old = rmw_add(fb + (mid >> 3) * 16, 1u);      // L1: 8 blocks
            if (old == 7u) {
                unsigned int old2 = rmw_add(fb + 16 * 16, 1u);         // L2: 16 bumps
                if (old2 == 15u) {
                    for (int j = 0; j < 16; ++j) rmw_add(fb + (17 + j) * 16, 1u);  // release fan-out
                }
            }
            unsigned int* rel = fb + (17 + (mid >> 3)) * 16;
            while (rmw_read(rel) == 0u) __builtin_amdgcn_s_sleep(2);
        }
        __syncthreads();
    }
    cSt[(size_t)grow * HH + e] = cReg0;
    cSt[(size_t)(grow + 64) * HH + e] = cReg1;
}

// ================= generic bf16 MFMA GEMM (x-part + phase 2) =================
template<int WR, int WC, int AMODE, int EPI>
__global__ __launch_bounds__(WR * WC * 64) void mm_kernel(
    const ushort* __restrict__ A, const ushort* __restrict__ hR,
    const ushort* __restrict__ BT, const float* __restrict__ bias,
    void* __restrict__ Cp, const float* __restrict__ ldw,
    const ushort* __restrict__ TH, float* __restrict__ outp,
    int ldaA, int ldb, int ldc, int K, int t, int RING, int tBase)
{
    constexpr int BM = WR * 64, BN = WC * 64, NT = WR * WC * 64, LS = 72;
    constexpr int AIT = BM * 8 / NT, BIT = BN * 8 / NT;
    __shared__ ushort As[BM * LS];
    __shared__ ushort Bs[BN * LS];
    const int tid = threadIdx.x;
    const int lane = tid & 63, wave = tid >> 6;
    const int wr = wave / WC, wc = wave % WC;

    int bx, by;
    if (AMODE == 2) {
        int vid = blockIdx.x;
        bx = (vid >> 3) & 7;
        by = ((vid >> 6) << 3) + (vid & 7);
        if (by >= t) return;        // t carries nM
    } else {
        bx = blockIdx.x; by = blockIdx.y;
    }
    const int m0 = by * BM, n0 = bx * BN;
    f32x4 acc[4][4] = {};

    auto gather = [&](int ktl, short8* vA, short8* vB) {
#pragma unroll
        for (int i = 0; i < AIT; ++i) {
            int id = tid + i * NT;
            int r = id >> 3, cc = id & 7;
            int k = ktl + cc * 8;
            short8 v;
            if (AMODE == 0) {
                v = *(const short8*)(A + (size_t)(m0 + r) * ldaA + k);
            } else {  // conv gather
                int ks = k >> 10, c = k & 1023;
                int tt = m0 >> 8, b = (m0 & 255) + r;
                int slot = (tBase + tt + ks) % RING;
                short8 hv = *(const short8*)(hR + (size_t)slot * BH2 + (size_t)b * 2048 + c);
                float s = ldw[((size_t)tt * 256 + b) * CSW + ks];
                ushort* pv = (ushort*)&hv;
                ushort* po = (ushort*)&v;
#pragma unroll
                for (int j = 0; j < 8; ++j) po[j] = f2bf(bf2f(pv[j]) * s);
            }
            vA[i] = v;
        }
#pragma unroll
        for (int i = 0; i < BIT; ++i) {
            int id = tid + i * NT;
            int n = id >> 3, cc = id & 7;
            vB[i] = *(const short8*)(BT + (size_t)(n0 + n) * ldb + ktl + cc * 8);
        }
    };

    short8 vA[AIT], vB[BIT];
    gather(0, vA, vB);

    for (int kt = 0; kt < K; kt += 64) {
#pragma unroll
        for (int i = 0; i < AIT; ++i) {
            int id = tid + i * NT;
            *(short8*)(As + (id >> 3) * LS + (id & 7) * 8) = vA[i];
        }
#pragma unroll
        for (int i = 0; i < BIT; ++i) {
            int id = tid + i * NT;
            *(short8*)(Bs + (id >> 3) * LS + (id & 7) * 8) = vB[i];
        }
        __syncthreads();
        if (kt + 64 < K) gather(kt + 64, vA, vB);
#pragma unroll
        for (int kf = 0; kf < 2; ++kf) {
            short8 aF[4], bF[4];
#pragma unroll
            for (int mi = 0; mi < 4; ++mi)
                aF[mi] = *(const short8*)(As + (wr * 64 + mi * 16 + (lane & 15)) * LS + kf * 32 + (lane >> 4) * 8);
#pragma unroll
            for (int ni = 0; ni < 4; ++ni)
                bF[ni] = *(const short8*)(Bs + (wc * 64 + ni * 16 + (lane & 15)) * LS + kf * 32 + (lane >> 4) * 8);
#pragma unroll
            for (int mi = 0; mi < 4; ++mi)
#pragma unroll
                for (int ni = 0; ni < 4; ++ni)
                    acc[mi][ni] = __builtin_amdgcn_mfma_f32_16x16x32_bf16(aF[mi], bF[ni], acc[mi][ni], 0, 0, 0);
        }
        __syncthreads();
    }
#pragma unroll
    for (int mi = 0; mi < 4; ++mi) {
#pragma unroll
        for (int ni = 0; ni < 4; ++ni) {
#pragma unroll
            for (int j = 0; j < 4; ++j) {
                int row = m0 + wr * 64 + mi * 16 + ((lane >> 4) << 2) + j;
                int col = n0 + wc * 64 + ni * 16 + (lane & 15);
                float v = acc[mi][ni][j];
                if (EPI != 0 && bias) v += bias[col];
                if (EPI == 0) {
                    ((float*)Cp)[(size_t)row * ldc + col] = v;
                } else if (EPI == 1) {
                    ((ushort*)Cp)[(size_t)row * ldc + col] = f2bf(v > 0.f ? v : 0.f);
                } else if (EPI == 2) {
                    ((ushort*)Cp)[(size_t)row * ldc + col] = f2bf(sigf(v));
                } else if (EPI == 3) {
                    int tt = row >> 8, b = row & 255;
                    int slot = (tBase + tt + 9) % RING;
                    float th = bf2f(TH[(size_t)row * HH + col]);
                    float h = bf2f(hR[(size_t)slot * BH2 + (size_t)b * 2048 + col]);
                    ((ushort*)Cp)[(size_t)row * ldc + col] = f2bf(th * v + h);
                } else {
                    int tt = tBase + (row >> 8), b = row & 255;
                    outp[((size_t)b * TT + tt) * OUTW + col] = sigf(v);
                }
            }
        }
    }
}

// ================= weight / input prep =================
__device__ __forceinline__ int pcol_to_orig(int n) {
    if (n < 4096) return 16 + (n & 3) * 1024 + (n >> 2);
    if (n < 4112) return n - 4096;
    return -1;
}

__global__ void build_whlP(const float* __restrict__ rw,
                           ushort* __restrict__ WhiP, ushort* __restrict__ WloP)
{
    size_t i = (size_t)blockIdx.x * 256 + threadIdx.x;
    if (i >= (size_t)4096 * 1024) return;
    int pc = (int)(i >> 10), k = (int)(i & 1023);
    int n = 16 + (pc & 3) * 1024 + (pc >> 2);
    float w = rw[(size_t)k * GG + n];
    ushort hi = f2bf(w);
    WhiP[i] = hi;
    WloP[i] = f2bf(w - bf2f(hi));
}

__global__ void build_wsp(const float* __restrict__ rw, ushort* __restrict__ WspT)
{
    int i = blockIdx.x * 256 + threadIdx.x;
    if (i >= 16 * 1024) return;
    int r = i >> 10, k = i & 1023;
    float w = rw[(size_t)k * GG + r];
    ushort hi = f2bf(w);
    WspT[i] = hi;
    WspT[16 * 1024 + i] = f2bf(w - bf2f(hi));
}

__global__ void build_wxt(const float* __restrict__ kw, const float* __restrict__ rw,
                          ushort* __restrict__ WxT)
{
    size_t i = (size_t)blockIdx.x * 256 + threadIdx.x;
    if (i >= (size_t)NPAD * KXP) return;
    int n = (int)(i / KXP), k = (int)(i % KXP);
    int seg = k / 288, kk = k - seg * 288;
    int oc = pcol_to_orig(n);
    float w = 0.f;
    if (oc >= 0 && seg < 3) {
        if (kk < 256)       w = kw[(size_t)kk * GG + oc];
        else if (kk == 256) w = kw[(size_t)256 * GG + oc];
        else if (kk == 257) w = rw[(size_t)1024 * GG + oc];
    }
    ushort hi = f2bf(w);
    WxT[i] = (seg == 1) ? f2bf(w - bf2f(hi)) : hi;
}

__global__ void build_bcp(const float* __restrict__ kb, const float* __restrict__ rb,
                          float* __restrict__ bcp)
{
    int i = blockIdx.x * 256 + threadIdx.x;
    if (i >= NPAD) return;
    int oc = pcol_to_orig(i);
    bcp[i] = (oc >= 0) ? kb[oc] + rb[oc] : 0.f;
}

__global__ void build_xac(const float* __restrict__ x, const float* __restrict__ tim,
                          ushort* __restrict__ XAc, int tBase, int Mloc)
{
    size_t i = (size_t)blockIdx.x * 256 + threadIdx.x;
    if (i >= (size_t)Mloc * KXP) return;
    int m = (int)(i / KXP), k = (int)(i % KXP);
    int t = tBase + (m >> 8), b = m & 255;
    int seg = k / 288, kk = k - seg * 288;
    float v = 0.f;
    if (seg < 3) {
        if (kk < 256)      v = x[((size_t)b * TT + t) * INW + kk];
        else if (kk < 258) v = tim[(size_t)b * TT + t];
    }
    ushort hi = f2bf(v);
    XAc[i] = (seg == 2) ? f2bf(v - bf2f(hi)) : hi;
}

__global__ void build_ctt(const float* __restrict__ cw, ushort* __restrict__ ctT)
{
    size_t i = (size_t)blockIdx.x * 256 + threadIdx.x;
    if (i >= (size_t)HH * HH * CSW) return;
    int o = (int)(i / (HH * CSW)), rest = (int)(i % (HH * CSW));
    int k = rest >> 10, c = rest & 1023;
    ctT[i] = f2bf(cw[((size_t)o * HH + c) * CSW + k]);
}

__global__ void build_swt(const float* __restrict__ sw, const float* __restrict__ sb,
                          ushort* __restrict__ swT, float* __restrict__ sbP)
{
    int i = blockIdx.x * 256 + threadIdx.x;
    if (i < 256 * 1024) {
        int n = i >> 10, k = i & 1023;
        swT[i] = f2bf(n < 170 ? sw[(size_t)k * 170 + n] : 0.f);
    }
    if (i < 256) sbP[i] = (i < 170) ? sb[i] : 0.f;
}

__global__ void build_rswt(const float* __restrict__ rsw, ushort* __restrict__ rswT)
{
    int i = blockIdx.x * 256 + threadIdx.x;
    if (i >= 1024 * 256) return;
    int n = i >> 8, k = i & 255;
    rswT[i] = f2bf(k < 170 ? rsw[(size_t)k * HH + n] : 0.f);
}

__global__ void build_owt(const float* __restrict__ ow, ushort* __restrict__ owT)
{
    int i = blockIdx.x * 256 + threadIdx.x;
    if (i >= OUTW * HH) return;
    int n = i >> 10, k = i & 1023;
    owT[i] = f2bf(ow[(size_t)k * OUTW + n]);
}

// ================= chunk helpers =================
__global__ void ld_chunk_kernel(const float* __restrict__ dist, float* __restrict__ ldC,
                                int tBase, int Mloc)
{
    int id = blockIdx.x * 256 + threadIdx.x;
    if (id >= Mloc) return;
    int t = tBase + (id >> 8), b = id & 255;
    float cv[CSW], cum = 0.f, mx = -1e30f;
#pragma unroll
    for (int k = 0; k < CSW; ++k) {
        int ts = t - 9 + k;
        cum += (ts >= 0) ? dist[(size_t)ts * BB + b] : 0.f;
        cv[k] = cum; mx = fmaxf(mx, cum);
    }
    float ss = 0.f;
#pragma unroll
    for (int k = 0; k < CSW; ++k) { cv[k] = expf(cv[k] - mx); ss += cv[k]; }
    float inv = 1.0f / ss;
#pragma unroll
    for (int k = 0; k < CSW; ++k) ldC[(size_t)id * CSW + k] = cv[k] * inv;
}

__global__ void mlh_kernel(const ushort* __restrict__ hR, const float* __restrict__ ldC,
                           ushort* __restrict__ MLH, int tBase, int RING)
{
    size_t id = (size_t)blockIdx.x * 256 + threadIdx.x;
    int m = (int)(id >> 7);
    int c0 = ((int)(id & 127)) << 3;
    int t = tBase + (m >> 8), b = m & 255;
    float acc[8] = {};
#pragma unroll
    for (int k = 0; k < CSW; ++k) {
        float s = ldC[(size_t)m * CSW + k];
        int slot = (t + k) % RING;
        short8 hv = *(const short8*)(hR + (size_t)slot * BH2 + (size_t)b * 2048 + c0);
        ushort* pv = (ushort*)&hv;
#pragma unroll
        for (int j = 0; j < 8; ++j) acc[j] += bf2f(pv[j]) * s;
    }
#pragma unroll
    for (int j = 0; j < 8; ++j) MLH[(size_t)m * HH + c0 + j] = f2bf(acc[j] * 0.1f);
}

// ================= launch =================
extern "C" void kernel_launch(void* const* d_in, const int* in_sizes, int n_in,
                              void* d_out, int out_size, void* d_ws, size_t ws_size,
                              hipStream_t stream)
{
    const float* x   = (const float*)d_in[0];
    const float* tim = (const float*)d_in[1];
    const float* kw  = (const float*)d_in[2];
    const float* kb  = (const float*)d_in[3];
    const float* rw  = (const float*)d_in[4];
    const float* rb  = (const float*)d_in[5];
    const float* sw  = (const float*)d_in[6];
    const float* sb  = (const float*)d_in[7];
    const float* rsw = (const float*)d_in[8];
    const float* rsb = (const float*)d_in[9];
    const float* cw  = (const float*)d_in[10];
    const float* cb  = (const float*)d_in[11];
    const float* ow  = (const float*)d_in[12];
    const float* ob  = (const float*)d_in[13];
    float* out  = (float*)d_out;
    float* dist = out + (size_t)BB * TT * OUTW;

    auto planSize = [&](int tch) -> size_t {
        size_t o = 0;
        auto al = [&](size_t bytes) { o += (bytes + 255) & ~(size_t)255; };
        int ring = tch + 9;
        al((size_t)ring * BH2 * 2);            // hRing (hi|lo)
        al((size_t)BB * HH * 4);               // cSt
        al((size_t)4096 * 1024 * 2);           // WhiP
        al((size_t)4096 * 1024 * 2);           // WloP
        al((size_t)32 * 1024 * 2);             // WspT
        al((size_t)NPAD * KXP * 2);            // WxT
        al((size_t)NPAD * 4);                  // bcp
        al((size_t)tch * 256 * NPAD * 4);      // xoX
        al((size_t)tch * 256 * KXP * 2);       // XAc
        al((size_t)TT * 256 * 16 * 4);         // fmAll (global-t indexed)
        al((size_t)tch * 256 * CSW * 4);       // ldC
        al((size_t)HH * HH * CSW * 2);         // ctT
        al((size_t)256 * 1024 * 2);            // swT
        al((size_t)256 * 4);                   // sbP
        al((size_t)1024 * 256 * 2);            // rswT
        al((size_t)OUTW * HH * 2);             // owT
        al((size_t)tch * 256 * HH * 2);        // MLH / RNN
        al((size_t)tch * 256 * 256 * 2);       // TH1
        al((size_t)tch * 256 * HH * 2);        // TH
        al(FLAGS_U32 * 4);                     // flags (global-t indexed)
        return o;
    };
    const int cands[4] = {16, 8, 4, 2};
    int TCH = 0;
    for (int ci = 0; ci < 4; ++ci)
        if (planSize(cands[ci]) <= ws_size) { TCH = cands[ci]; break; }
    if (TCH == 0) return;   // diagnostic: output stays zero -> absmax ~0.83
    const int RING = TCH + 9;
    const int Mloc = TCH * 256;
    const int nM = Mloc / 128;

    char* base = (char*)d_ws;
    size_t off = 0;
    auto alloc = [&](size_t bytes) { char* p = base + off; off += (bytes + 255) & ~(size_t)255; return p; };
    ushort* hRing = (ushort*)alloc((size_t)RING * BH2 * 2);
    float*  cSt   = (float*) alloc((size_t)BB * HH * 4);
    ushort* WhiP  = (ushort*)alloc((size_t)4096 * 1024 * 2);
    ushort* WloP  = (ushort*)alloc((size_t)4096 * 1024 * 2);
    ushort* WspT  = (ushort*)alloc((size_t)32 * 1024 * 2);
    ushort* WxT   = (ushort*)alloc((size_t)NPAD * KXP * 2);
    float*  bcp   = (float*) alloc((size_t)NPAD * 4);
    float*  xoX   = (float*) alloc((size_t)Mloc * NPAD * 4);
    ushort* XAc   = (ushort*)alloc((size_t)Mloc * KXP * 2);
    float*  fmAll = (float*) alloc((size_t)TT * 256 * 16 * 4);
    float*  ldC   = (float*) alloc((size_t)Mloc * CSW * 4);
    ushort* ctT   = (ushort*)alloc((size_t)HH * HH * CSW * 2);
    ushort* swT   = (ushort*)alloc((size_t)256 * 1024 * 2);
    float*  sbP   = (float*) alloc((size_t)256 * 4);
    ushort* rswT  = (ushort*)alloc((size_t)1024 * 256 * 2);
    ushort* owT   = (ushort*)alloc((size_t)OUTW * HH * 2);
    ushort* MLH   = (ushort*)alloc((size_t)Mloc * HH * 2);
    ushort* TH1   = (ushort*)alloc((size_t)Mloc * 256 * 2);
    ushort* TH    = (ushort*)alloc((size_t)Mloc * HH * 2);
    unsigned int* flags = (unsigned int*)alloc(FLAGS_U32 * 4);
    ushort* RNN   = MLH;

    hipMemsetAsync(hRing, 0, (size_t)9 * BH2 * 2, stream);
    hipMemsetAsync(cSt, 0, (size_t)BB * HH * 4, stream);
    hipMemsetAsync(flags, 0, FLAGS_U32 * 4, stream);

    build_whlP<<<(int)(((size_t)4096 * 1024 + 255) / 256), 256, 0, stream>>>(rw, WhiP, WloP);
    build_wsp<<<(16 * 1024 + 255) / 256, 256, 0, stream>>>(rw, WspT);
    build_wxt<<<(int)(((size_t)NPAD * KXP + 255) / 256), 256, 0, stream>>>(kw, rw, WxT);
    build_bcp<<<(NPAD + 255) / 256, 256, 0, stream>>>(kb, rb, bcp);
    build_ctt<<<(int)(((size_t)HH * HH * CSW + 255) / 256), 256, 0, stream>>>(cw, ctT);
    build_swt<<<(256 * 1024 + 255) / 256, 256, 0, stream>>>(sw, sb, swT, sbP);
    build_rswt<<<(1024 * 256 + 255) / 256, 256, 0, stream>>>(rsw, rswT);
    build_owt<<<(OUTW * HH + 255) / 256, 256, 0, stream>>>(ow, owT);

    for (int tBase = 0; tBase < TT; tBase += TCH) {
        // ---- batched x-part: xoX = XAc @ WxT (permuted N) ----
        build_xac<<<(int)(((size_t)Mloc * KXP + 255) / 256), 256, 0, stream>>>(
            x, tim, XAc, tBase, Mloc);
        mm_kernel<2, 2, 0, 0><<<dim3(33, Mloc / 128), 256, 0, stream>>>(
            XAc, nullptr, WxT, nullptr, xoX, nullptr, nullptr, nullptr,
            KXP, KXP, NPAD, KXP, 0, RING, tBase);
        // ---- persistent scan (RMW-only sync) ----
        scan_kernel<<<NBLK, 512, 0, stream>>>(
            WhiP, WloP, WspT, hRing, cSt, xoX, bcp, fmAll, dist, flags,
            tBase, TCH, RING);
        // ---- batched phase-2 ----
        ld_chunk_kernel<<<(Mloc + 255) / 256, 256, 0, stream>>>(dist, ldC, tBase, Mloc);
        mlh_kernel<<<Mloc / 2, 256, 0, stream>>>(hRing, ldC, MLH, tBase, RING);
        mm_kernel<2, 2, 0, 1><<<dim3(2, Mloc / 128), 256, 0, stream>>>(
            MLH, nullptr, swT, sbP, TH1, nullptr, nullptr, nullptr,
            1024, 1024, 256, 1024, 0, RING, tBase);
        mm_kernel<2, 2, 0, 2><<<dim3(8, Mloc / 128), 256, 0, stream>>>(
            TH1, nullptr, rswT, rsb, TH, nullptr, nullptr, nullptr,
            256, 256, 1024, 256, 0, RING, tBase);
        mm_kernel<2, 2, 2, 3><<<dim3(((nM + 7) / 8) * 64), 256, 0, stream>>>(
            nullptr, hRing, ctT, cb, RNN, ldC, TH, nullptr,
            0, HH * CSW, 1024, HH * CSW, nM, RING, tBase);
        mm_kernel<4, 1, 0, 4><<<dim3(1, Mloc / 256), 256, 0, stream>>>(
            RNN, nullptr, owT, ob, nullptr, nullptr, nullptr, out,
            1024, 1024, 0, 1024, 0, RING, tBase);
    }
}

// Round 11
// 21094.028 us; speedup vs baseline: 2.4505x; 1.0145x over previous
//
#include <hip/hip_runtime.h>
#include <hip/hip_bf16.h>
#include <math.h>

#define BB 256
#define TT 256
#define INW 256
#define HH 1024
#define LL 8
#define CSW 10
#define OUTW 64
#define GG 4112
#define KXP 896            // x-part GEMM K: 3*288 = 864 padded
#define NPAD 4224          // 4112 padded to 33*128
#define BH2 (BB * 2048)    // h ring slot stride: [b][0..1023]=hi, [1024..2047]=lo
#define NBLK 256
// flags: per (global t, group mt): 64 slots x 16 u32 (64B) each.
#define FLAGS_U32 ((size_t)TT * 2 * 64 * 16)

typedef __attribute__((ext_vector_type(8))) short short8;
typedef __attribute__((ext_vector_type(4))) float f32x4;

__device__ __forceinline__ float bf2f(ushort u) {
    union { float f; unsigned int i; } v; v.i = ((unsigned int)u) << 16; return v.f;
}
__device__ __forceinline__ ushort f2bf(float f) {
    __hip_bfloat16 h = __float2bfloat16(f);
    return *(ushort*)&h;
}
__device__ __forceinline__ float sigf(float v) { return 1.0f / (1.0f + expf(-v)); }

// ---- IF-visible write-through stores ----
__device__ __forceinline__ void st_wt_f32x4(float* p, f32x4 v) {
    asm volatile("global_store_dwordx4 %0, %1, off sc0 sc1" :: "v"(p), "v"(v) : "memory");
}
// ---- coherent RMW helpers (execute at LLC; no stale-L2 ambiguity) ----
__device__ __forceinline__ unsigned int rmw_add(unsigned int* p, unsigned int v) {
    return __hip_atomic_fetch_add(p, v, __ATOMIC_RELAXED, __HIP_MEMORY_SCOPE_AGENT);
}
__device__ __forceinline__ unsigned int rmw_read(unsigned int* p) {
    return __hip_atomic_fetch_add(p, 0u, __ATOMIC_RELAXED, __HIP_MEMORY_SCOPE_AGENT);
}

// ================= persistent scan kernel v5 (depth-4 prefetch) =================
__global__ __launch_bounds__(512) void scan_kernel(
    const ushort* __restrict__ WhiP, const ushort* __restrict__ WloP,
    const ushort* __restrict__ WspT, ushort* __restrict__ hR,
    float* __restrict__ cSt, const float* __restrict__ xoX,
    const float* __restrict__ bcp, float* __restrict__ fmAll,
    float* __restrict__ dist, unsigned int* __restrict__ flags,
    int tBase, int TCH, int RING)
{
    __shared__ ushort Wh_s[32 * 1032];      // 66048 B
    __shared__ ushort Wl_s[32 * 1032];      // 66048 B
    __shared__ ushort AhAl_s[2 * 128 * 36]; // 18432 B, aliased as xo f32 after K-loop
    __shared__ ushort Wsp_s[32 * 72];       // 4608 B, aliased as sp f32 after K-loop
    __shared__ ushort hOut_s[128 * 8];      // 2048 B
    __shared__ ushort loOut_s[128 * 8];     // 2048 B
    __shared__ float bc_s[32];

    ushort* Ah_s = AhAl_s;
    ushort* Al_s = AhAl_s + 128 * 36;

    const int tid = threadIdx.x, lane = tid & 63, wave = tid >> 6;
    const int bid = blockIdx.x;
    const int xcd = bid & 7, jj = bid >> 3;
    const int mt = xcd >> 2;              // group
    const int nt = (xcd & 3) * 32 + jj;   // 0..127
    const int m0 = mt * 128;
    const int pc0 = nt * 32;
    const bool isHelper = (jj == 0);
    const int hid = xcd;
    const int mid = jj * 4 + (xcd & 3);   // member id within group [0,128)
    const int wr = wave >> 1, wc = wave & 1;

    // ---- load W slice to LDS (once) ----
    for (int i = tid; i < 32 * 128; i += 512) {
        int col = i >> 7, k8 = (i & 127) * 8;
        *(short8*)(Wh_s + col * 1032 + k8) = *(const short8*)(WhiP + (size_t)(pc0 + col) * 1024 + k8);
        *(short8*)(Wl_s + col * 1032 + k8) = *(const short8*)(WloP + (size_t)(pc0 + col) * 1024 + k8);
    }
    if (tid < 32) bc_s[tid] = bcp[pc0 + tid];

    const int rloc = tid >> 3, uu = tid & 7;
    const int grow = m0 + rloc;
    const int e = nt * 8 + uu;
    const int ll = e >> 7;
    float cReg0 = cSt[(size_t)grow * HH + e];
    float cReg1 = cSt[(size_t)(grow + 64) * HH + e];
    __syncthreads();

    const int arow = tid >> 2, ak8 = (tid & 3) * 8;
    const int spHalf = tid >> 6, spRow = (tid >> 2) & 15, spK8 = (tid & 3) * 8; // tid<128

    for (int tt = 0; tt < TCH; ++tt) {
        const int t = tBase + tt;
        unsigned int* fb = flags + ((size_t)(t * 2 + mt) * 64) * 16;
        const ushort* hA = hR + (size_t)((t + 8) % RING) * BH2 + (size_t)m0 * 2048;
        f32x4 aHH0 = {}, aHL0 = {}, aLH0 = {}, aHH1 = {}, aHL1 = {}, aLH1 = {};
        f32x4 sHH = {}, sHL = {}, sLH = {};
        // ---- depth-4 register prefetch ----
        short8 pH[4], pL[4], pS[4];
#pragma unroll
        for (int d = 0; d < 4; ++d) {
            int kn = d * 32;
            pH[d] = *(const short8*)(hA + (size_t)arow * 2048 + kn + ak8);
            pL[d] = *(const short8*)(hA + (size_t)arow * 2048 + 1024 + kn + ak8);
        }
        if (isHelper && tid < 128) {
#pragma unroll
            for (int d = 0; d < 4; ++d)
                pS[d] = *(const short8*)(WspT + (size_t)(spHalf * 16 + spRow) * 1024 + d * 32 + spK8);
        }

#pragma unroll 4
        for (int it = 0; it < 32; ++it) {
            const int sel = it & 3;
            *(short8*)(Ah_s + arow * 36 + ak8) = pH[sel];
            *(short8*)(Al_s + arow * 36 + ak8) = pL[sel];
            if (isHelper && tid < 128)
                *(short8*)(Wsp_s + (spHalf * 16 + spRow) * 72 + spK8) = pS[sel];
            __syncthreads();
            if (it + 4 < 32) {
                int kn = (it + 4) * 32;
                pH[sel] = *(const short8*)(hA + (size_t)arow * 2048 + kn + ak8);
                pL[sel] = *(const short8*)(hA + (size_t)arow * 2048 + 1024 + kn + ak8);
                if (isHelper && tid < 128)
                    pS[sel] = *(const short8*)(WspT + (size_t)(spHalf * 16 + spRow) * 1024 + kn + spK8);
            }
            const int fr = lane & 15, fk = (lane >> 4) * 8;
            short8 bH = *(const short8*)(Wh_s + (wc * 16 + fr) * 1032 + it * 32 + fk);
            short8 bL = *(const short8*)(Wl_s + (wc * 16 + fr) * 1032 + it * 32 + fk);
            short8 aH0 = *(const short8*)(Ah_s + (wr * 32 + fr) * 36 + fk);
            short8 aL0 = *(const short8*)(Al_s + (wr * 32 + fr) * 36 + fk);
            short8 aH1 = *(const short8*)(Ah_s + (wr * 32 + 16 + fr) * 36 + fk);
            short8 aL1 = *(const short8*)(Al_s + (wr * 32 + 16 + fr) * 36 + fk);
            aHH0 = __builtin_amdgcn_mfma_f32_16x16x32_bf16(aH0, bH, aHH0, 0, 0, 0);
            aHH1 = __builtin_amdgcn_mfma_f32_16x16x32_bf16(aH1, bH, aHH1, 0, 0, 0);
            aHL0 = __builtin_amdgcn_mfma_f32_16x16x32_bf16(aH0, bL, aHL0, 0, 0, 0);
            aHL1 = __builtin_amdgcn_mfma_f32_16x16x32_bf16(aH1, bL, aHL1, 0, 0, 0);
            aLH0 = __builtin_amdgcn_mfma_f32_16x16x32_bf16(aL0, bH, aLH0, 0, 0, 0);
            aLH1 = __builtin_amdgcn_mfma_f32_16x16x32_bf16(aL1, bH, aLH1, 0, 0, 0);
            if (isHelper && wave < 2) {
                int srl = (hid & 3) * 32 + wave * 16;
                short8 sH = *(const short8*)(Ah_s + (srl + fr) * 36 + fk);
                short8 sL = *(const short8*)(Al_s + (srl + fr) * 36 + fk);
                short8 wH = *(const short8*)(Wsp_s + fr * 72 + fk);
                short8 wL = *(const short8*)(Wsp_s + (16 + fr) * 72 + fk);
                sHH = __builtin_amdgcn_mfma_f32_16x16x32_bf16(sH, wH, sHH, 0, 0, 0);
                sHL = __builtin_amdgcn_mfma_f32_16x16x32_bf16(sH, wL, sHL, 0, 0, 0);
                sLH = __builtin_amdgcn_mfma_f32_16x16x32_bf16(sL, wH, sLH, 0, 0, 0);
            }
            __syncthreads();
        }
        // ---- xo -> LDS (alias A), sp -> LDS (alias Wsp) ----
        float* xo_s = (float*)AhAl_s;   // [128][36]
        float* sp_s = (float*)Wsp_s;    // [32][20]
        f32x4 acc0 = aHH0 + aHL0 + aLH0;
        f32x4 acc1 = aHH1 + aHL1 + aLH1;
#pragma unroll
        for (int j = 0; j < 4; ++j) {
            int r0 = wr * 32 + ((lane >> 4) << 2) + j;
            int col = wc * 16 + (lane & 15);
            xo_s[r0 * 36 + col] = acc0[j];
            xo_s[(r0 + 16) * 36 + col] = acc1[j];
        }
        if (isHelper && wave < 2) {
            f32x4 asp = sHH + sHL + sLH;
#pragma unroll
            for (int j = 0; j < 4; ++j) {
                int srow = wave * 16 + ((lane >> 4) << 2) + j;
                sp_s[srow * 20 + (lane & 15)] = asp[j];
            }
        }
        __syncthreads();
        // ---- helpers: softmax -> fm/im pairs (write-through), hCnt fan-out bumps ----
        if (isHelper) {
            if (tid < 32) {
                int r = tid, growS = hid * 32 + r;
                const float* xxs = xoX + ((size_t)tt * 256 + growS) * NPAD + 4096;
                float xr[16];
#pragma unroll
                for (int q = 0; q < 16; ++q) xr[q] = sp_s[r * 20 + q] + xxs[q] + bcp[4096 + q];
                float m1 = -1e30f, m2 = -1e30f;
                for (int q = 0; q < 8; ++q) { m1 = fmaxf(m1, xr[q]); m2 = fmaxf(m2, xr[8 + q]); }
                float e1[8], e2[8], s1 = 0.f, s2 = 0.f;
                for (int q = 0; q < 8; ++q) {
                    e1[q] = expf(xr[q] - m1); s1 += e1[q];
                    e2[q] = expf(xr[8 + q] - m2); s2 += e2[q];
                }
                float s1i = 1.0f / s1, s2i = 1.0f / s2;
                float cum = 0.f, mean = 0.f, fmv[8], imv[8];
                for (int q = 0; q < 8; ++q) { cum += e1[q] * s1i; fmv[q] = cum; mean += cum; }
                float rc = 0.f;
                for (int q = 7; q >= 0; --q) { rc += e2[q] * s2i; imv[q] = rc; }
                float* fp = fmAll + ((size_t)t * 256 + growS) * 16;
                f32x4 v0 = {fmv[0], imv[0], fmv[1], imv[1]};
                f32x4 v1 = {fmv[2], imv[2], fmv[3], imv[3]};
                f32x4 v2 = {fmv[4], imv[4], fmv[5], imv[5]};
                f32x4 v3 = {fmv[6], imv[6], fmv[7], imv[7]};
                st_wt_f32x4(fp, v0); st_wt_f32x4(fp + 4, v1);
                st_wt_f32x4(fp + 8, v2); st_wt_f32x4(fp + 12, v3);
                dist[(size_t)t * BB + growS] = 1.0f - mean * 0.125f;
            }
            asm volatile("s_waitcnt vmcnt(0)" ::: "memory");
            if (tid < 16) rmw_add(fb + (33 + tid) * 16, 1u);
        }
        // ---- consumer: xv loads + HOISTED gate transcendentals, then wait ----
        const float* xxg0 = xoX + ((size_t)tt * 256 + grow) * NPAD + e * 4;
        const float* xxg1 = xoX + ((size_t)tt * 256 + grow + 64) * NPAD + e * 4;
        f32x4 xv0 = *(const f32x4*)xxg0;
        f32x4 xv1 = *(const f32x4*)xxg1;
        float bc0 = bc_s[uu * 4 + 0], bc1 = bc_s[uu * 4 + 1];
        float bc2 = bc_s[uu * 4 + 2], bc3 = bc_s[uu * 4 + 3];
        f32x4 g0 = *(const f32x4*)(xo_s + rloc * 36 + uu * 4);
        f32x4 g1 = *(const f32x4*)(xo_s + (rloc + 64) * 36 + uu * 4);
        float f0  = sigf(g0[0] + xv0[0] + bc0);
        float i0  = sigf(g0[1] + xv0[1] + bc1);
        float o0  = sigf(g0[2] + xv0[2] + bc2);
        float ci0 = tanhf(g0[3] + xv0[3] + bc3);
        float f1  = sigf(g1[0] + xv1[0] + bc0);
        float i1  = sigf(g1[1] + xv1[1] + bc1);
        float o1  = sigf(g1[2] + xv1[2] + bc2);
        float ci1 = tanhf(g1[3] + xv1[3] + bc3);
        if (tid == 0) {
            unsigned int* hc = fb + (33 + (mid >> 3)) * 16;
            while (rmw_read(hc) < 4u) __builtin_amdgcn_s_sleep(1);
        }
        __syncthreads();
        // ---- cell update (c in registers), pack h via LDS ----
        {
            const float* fb0 = fmAll + ((size_t)t * 256 + grow) * 16 + 2 * ll;
            const float* fb1 = fmAll + ((size_t)t * 256 + grow + 64) * 16 + 2 * ll;
            float fmv0 = fb0[0], imv0 = fb0[1];
            float fmv1 = fb1[0], imv1 = fb1[1];
            {
                float OV = fmv0 * imv0;
                float cn = OV * (f0 * cReg0 + i0 * ci0) + (fmv0 - OV) * cReg0 + (imv0 - OV) * ci0;
                float hn = o0 * tanhf(cn);
                cReg0 = cn;
                ushort hi = f2bf(hn);
                hOut_s[rloc * 8 + uu] = hi;
                loOut_s[rloc * 8 + uu] = f2bf(hn - bf2f(hi));
            }
            {
                float OV = fmv1 * imv1;
                float cn = OV * (f1 * cReg1 + i1 * ci1) + (fmv1 - OV) * cReg1 + (imv1 - OV) * ci1;
                float hn = o1 * tanhf(cn);
                cReg1 = cn;
                ushort hi = f2bf(hn);
                hOut_s[(rloc + 64) * 8 + uu] = hi;
                loOut_s[(rloc + 64) * 8 + uu] = f2bf(hn - bf2f(hi));
            }
        }
        __syncthreads();
        {
            int slot = (t + 9) % RING;
            if (tid < 128) {
                ushort* hp = hR + (size_t)slot * BH2 + (size_t)(m0 + tid) * 2048 + nt * 8;
                st_wt_f32x4((float*)hp, *(f32x4*)(hOut_s + tid * 8));
            } else if (tid < 256) {
                int row = tid - 128;
                ushort* hp = hR + (size_t)slot * BH2 + (size_t)(m0 + row) * 2048 + 1024 + nt * 8;
                st_wt_f32x4((float*)hp, *(f32x4*)(loOut_s + row * 8));
            }
        }
        // ---- 3-level group barrier (all RMW) ----
        asm volatile("s_waitcnt vmcnt(0)" ::: "memory");
        __syncthreads();
        if (tid == 0) {
            unsigned int old = rmw_add(fb + (mid >> 3) * 16, 1u);
            if (old == 7u) {
                unsigned int old2 = rmw_add(fb + 16 * 16, 1u);
                if (old2 == 15u) {
                    for (int j = 0; j < 16; ++j) rmw_add(fb + (17 + j) * 16, 1u);
                }
            }
            unsigned int* rel = fb + (17 + (mid >> 3)) * 16;
            while (rmw_read(rel) == 0u) __builtin_amdgcn_s_sleep(1);
        }
        __syncthreads();
    }
    cSt[(size_t)grow * HH + e] = cReg0;
    cSt[(size_t)(grow + 64) * HH + e] = cReg1;
}

// ================= generic bf16 MFMA GEMM (x-part + phase 2) =================
template<int WR, int WC, int AMODE, int EPI>
__global__ __launch_bounds__(WR * WC * 64) void mm_kernel(
    const ushort* __restrict__ A, const ushort* __restrict__ hR,
    const ushort* __restrict__ BT, const float* __restrict__ bias,
    void* __restrict__ Cp, const float* __restrict__ ldw,
    const ushort* __restrict__ TH, float* __restrict__ outp,
    int ldaA, int ldb, int ldc, int K, int t, int RING, int tBase)
{
    constexpr int BM = WR * 64, BN = WC * 64, NT = WR * WC * 64, LS = 72;
    constexpr int AIT = BM * 8 / NT, BIT = BN * 8 / NT;
    __shared__ ushort As[BM * LS];
    __shared__ ushort Bs[BN * LS];
    const int tid = threadIdx.x;
    const int lane = tid & 63, wave = tid >> 6;
    const int wr = wave / WC, wc = wave % WC;

    int bx, by;
    if (AMODE == 2) {
        int vid = blockIdx.x;
        bx = (vid >> 3) & 7;
        by = ((vid >> 6) << 3) + (vid & 7);
        if (by >= t) return;        // t carries nM
    } else {
        bx = blockIdx.x; by = blockIdx.y;
    }
    const int m0 = by * BM, n0 = bx * BN;
    f32x4 acc[4][4] = {};

    auto gather = [&](int ktl, short8* vA, short8* vB) {
#pragma unroll
        for (int i = 0; i < AIT; ++i) {
            int id = tid + i * NT;
            int r = id >> 3, cc = id & 7;
            int k = ktl + cc * 8;
            short8 v;
            if (AMODE == 0) {
                v = *(const short8*)(A + (size_t)(m0 + r) * ldaA + k);
            } else {  // conv gather
                int ks = k >> 10, c = k & 1023;
                int tt = m0 >> 8, b = (m0 & 255) + r;
                int slot = (tBase + tt + ks) % RING;
                short8 hv = *(const short8*)(hR + (size_t)slot * BH2 + (size_t)b * 2048 + c);
                float s = ldw[((size_t)tt * 256 + b) * CSW + ks];
                ushort* pv = (ushort*)&hv;
                ushort* po = (ushort*)&v;
#pragma unroll
                for (int j = 0; j < 8; ++j) po[j] = f2bf(bf2f(pv[j]) * s);
            }
            vA[i] = v;
        }
#pragma unroll
        for (int i = 0; i < BIT; ++i) {
            int id = tid + i * NT;
            int n = id >> 3, cc = id & 7;
            vB[i] = *(const short8*)(BT + (size_t)(n0 + n) * ldb + ktl + cc * 8);
        }
    };

    short8 vA[AIT], vB[BIT];
    gather(0, vA, vB);

    for (int kt = 0; kt < K; kt += 64) {
#pragma unroll
        for (int i = 0; i < AIT; ++i) {
            int id = tid + i * NT;
            *(short8*)(As + (id >> 3) * LS + (id & 7) * 8) = vA[i];
        }
#pragma unroll
        for (int i = 0; i < BIT; ++i) {
            int id = tid + i * NT;
            *(short8*)(Bs + (id >> 3) * LS + (id & 7) * 8) = vB[i];
        }
        __syncthreads();
        if (kt + 64 < K) gather(kt + 64, vA, vB);
#pragma unroll
        for (int kf = 0; kf < 2; ++kf) {
            short8 aF[4], bF[4];
#pragma unroll
            for (int mi = 0; mi < 4; ++mi)
                aF[mi] = *(const short8*)(As + (wr * 64 + mi * 16 + (lane & 15)) * LS + kf * 32 + (lane >> 4) * 8);
#pragma unroll
            for (int ni = 0; ni < 4; ++ni)
                bF[ni] = *(const short8*)(Bs + (wc * 64 + ni * 16 + (lane & 15)) * LS + kf * 32 + (lane >> 4) * 8);
#pragma unroll
            for (int mi = 0; mi < 4; ++mi)
#pragma unroll
                for (int ni = 0; ni < 4; ++ni)
                    acc[mi][ni] = __builtin_amdgcn_mfma_f32_16x16x32_bf16(aF[mi], bF[ni], acc[mi][ni], 0, 0, 0);
        }
        __syncthreads();
    }
#pragma unroll
    for (int mi = 0; mi < 4; ++mi) {
#pragma unroll
        for (int ni = 0; ni < 4; ++ni) {
#pragma unroll
            for (int j = 0; j < 4; ++j) {
                int row = m0 + wr * 64 + mi * 16 + ((lane >> 4) << 2) + j;
                int col = n0 + wc * 64 + ni * 16 + (lane & 15);
                float v = acc[mi][ni][j];
                if (EPI != 0 && bias) v += bias[col];
                if (EPI == 0) {
                    ((float*)Cp)[(size_t)row * ldc + col] = v;
                } else if (EPI == 1) {
                    ((ushort*)Cp)[(size_t)row * ldc + col] = f2bf(v > 0.f ? v : 0.f);
                } else if (EPI == 2) {
                    ((ushort*)Cp)[(size_t)row * ldc + col] = f2bf(sigf(v));
                } else if (EPI == 3) {
                    int tt = row >> 8, b = row & 255;
                    int slot = (tBase + tt + 9) % RING;
                    float th = bf2f(TH[(size_t)row * HH + col]);
                    float h = bf2f(hR[(size_t)slot * BH2 + (size_t)b * 2048 + col]);
                    ((ushort*)Cp)[(size_t)row * ldc + col] = f2bf(th * v + h);
                } else {
                    int tt = tBase + (row >> 8), b = row & 255;
                    outp[((size_t)b * TT + tt) * OUTW + col] = sigf(v);
                }
            }
        }
    }
}

// ================= weight / input prep =================
__device__ __forceinline__ int pcol_to_orig(int n) {
    if (n < 4096) return 16 + (n & 3) * 1024 + (n >> 2);
    if (n < 4112) return n - 4096;
    return -1;
}

__global__ void build_whlP(const float* __restrict__ rw,
                           ushort* __restrict__ WhiP, ushort* __restrict__ WloP)
{
    size_t i = (size_t)blockIdx.x * 256 + threadIdx.x;
    if (i >= (size_t)4096 * 1024) return;
    int pc = (int)(i >> 10), k = (int)(i & 1023);
    int n = 16 + (pc & 3) * 1024 + (pc >> 2);
    float w = rw[(size_t)k * GG + n];
    ushort hi = f2bf(w);
    WhiP[i] = hi;
    WloP[i] = f2bf(w - bf2f(hi));
}

__global__ void build_wsp(const float* __restrict__ rw, ushort* __restrict__ WspT)
{
    int i = blockIdx.x * 256 + threadIdx.x;
    if (i >= 16 * 1024) return;
    int r = i >> 10, k = i & 1023;
    float w = rw[(size_t)k * GG + r];
    ushort hi = f2bf(w);
    WspT[i] = hi;
    WspT[16 * 1024 + i] = f2bf(w - bf2f(hi));
}

__global__ void build_wxt(const float* __restrict__ kw, const float* __restrict__ rw,
                          ushort* __restrict__ WxT)
{
    size_t i = (size_t)blockIdx.x * 256 + threadIdx.x;
    if (i >= (size_t)NPAD * KXP) return;
    int n = (int)(i / KXP), k = (int)(i % KXP);
    int seg = k / 288, kk = k - seg * 288;
    int oc = pcol_to_orig(n);
    float w = 0.f;
    if (oc >= 0 && seg < 3) {
        if (kk < 256)       w = kw[(size_t)kk * GG + oc];
        else if (kk == 256) w = kw[(size_t)256 * GG + oc];
        else if (kk == 257) w = rw[(size_t)1024 * GG + oc];
    }
    ushort hi = f2bf(w);
    WxT[i] = (seg == 1) ? f2bf(w - bf2f(hi)) : hi;
}

__global__ void build_bcp(const float* __restrict__ kb, const float* __restrict__ rb,
                          float* __restrict__ bcp)
{
    int i = blockIdx.x * 256 + threadIdx.x;
    if (i >= NPAD) return;
    int oc = pcol_to_orig(i);
    bcp[i] = (oc >= 0) ? kb[oc] + rb[oc] : 0.f;
}

__global__ void build_xac(const float* __restrict__ x, const float* __restrict__ tim,
                          ushort* __restrict__ XAc, int tBase, int Mloc)
{
    size_t i = (size_t)blockIdx.x * 256 + threadIdx.x;
    if (i >= (size_t)Mloc * KXP) return;
    int m = (int)(i / KXP), k = (int)(i % KXP);
    int t = tBase + (m >> 8), b = m & 255;
    int seg = k / 288, kk = k - seg * 288;
    float v = 0.f;
    if (seg < 3) {
        if (kk < 256)      v = x[((size_t)b * TT + t) * INW + kk];
        else if (kk < 258) v = tim[(size_t)b * TT + t];
    }
    ushort hi = f2bf(v);
    XAc[i] = (seg == 2) ? f2bf(v - bf2f(hi)) : hi;
}

__global__ void build_ctt(const float* __restrict__ cw, ushort* __restrict__ ctT)
{
    size_t i = (size_t)blockIdx.x * 256 + threadIdx.x;
    if (i >= (size_t)HH * HH * CSW) return;
    int o = (int)(i / (HH * CSW)), rest = (int)(i % (HH * CSW));
    int k = rest >> 10, c = rest & 1023;
    ctT[i] = f2bf(cw[((size_t)o * HH + c) * CSW + k]);
}

__global__ void build_swt(const float* __restrict__ sw, const float* __restrict__ sb,
                          ushort* __restrict__ swT, float* __restrict__ sbP)
{
    int i = blockIdx.x * 256 + threadIdx.x;
    if (i < 256 * 1024) {
        int n = i >> 10, k = i & 1023;
        swT[i] = f2bf(n < 170 ? sw[(size_t)k * 170 + n] : 0.f);
    }
    if (i < 256) sbP[i] = (i < 170) ? sb[i] : 0.f;
}

__global__ void build_rswt(const float* __restrict__ rsw, ushort* __restrict__ rswT)
{
    int i = blockIdx.x * 256 + threadIdx.x;
    if (i >= 1024 * 256) return;
    int n = i >> 8, k = i & 255;
    rswT[i] = f2bf(k < 170 ? rsw[(size_t)k * HH + n] : 0.f);
}

__global__ void build_owt(const float* __restrict__ ow, ushort* __restrict__ owT)
{
    int i = blockIdx.x * 256 + threadIdx.x;
    if (i >= OUTW * HH) return;
    int n = i >> 10, k = i & 1023;
    owT[i] = f2bf(ow[(size_t)k * OUTW + n]);
}

// ================= chunk helpers =================
__global__ void ld_chunk_kernel(const float* __restrict__ dist, float* __restrict__ ldC,
                                int tBase, int Mloc)
{
    int id = blockIdx.x * 256 + threadIdx.x;
    if (id >= Mloc) return;
    int t = tBase + (id >> 8), b = id & 255;
    float cv[CSW], cum = 0.f, mx = -1e30f;
#pragma unroll
    for (int k = 0; k < CSW; ++k) {
        int ts = t - 9 + k;
        cum += (ts >= 0) ? dist[(size_t)ts * BB + b] : 0.f;
        cv[k] = cum; mx = fmaxf(mx, cum);
    }
    float ss = 0.f;
#pragma unroll
    for (int k = 0; k < CSW; ++k) { cv[k] = expf(cv[k] - mx); ss += cv[k]; }
    float inv = 1.0f / ss;
#pragma unroll
    for (int k = 0; k < CSW; ++k) ldC[(size_t)id * CSW + k] = cv[k] * inv;
}

__global__ void mlh_kernel(const ushort* __restrict__ hR, const float* __restrict__ ldC,
                           ushort* __restrict__ MLH, int tBase, int RING)
{
    size_t id = (size_t)blockIdx.x * 256 + threadIdx.x;
    int m = (int)(id >> 7);
    int c0 = ((int)(id & 127)) << 3;
    int t = tBase + (m >> 8), b = m & 255;
    float acc[8] = {};
#pragma unroll
    for (int k = 0; k < CSW; ++k) {
        float s = ldC[(size_t)m * CSW + k];
        int slot = (t + k) % RING;
        short8 hv = *(const short8*)(hR + (size_t)slot * BH2 + (size_t)b * 2048 + c0);
        ushort* pv = (ushort*)&hv;
#pragma unroll
        for (int j = 0; j < 8; ++j) acc[j] += bf2f(pv[j]) * s;
    }
#pragma unroll
    for (int j = 0; j < 8; ++j) MLH[(size_t)m * HH + c0 + j] = f2bf(acc[j] * 0.1f);
}

// ================= launch =================
extern "C" void kernel_launch(void* const* d_in, const int* in_sizes, int n_in,
                              void* d_out, int out_size, void* d_ws, size_t ws_size,
                              hipStream_t stream)
{
    const float* x   = (const float*)d_in[0];
    const float* tim = (const float*)d_in[1];
    const float* kw  = (const float*)d_in[2];
    const float* kb  = (const float*)d_in[3];
    const float* rw  = (const float*)d_in[4];
    const float* rb  = (const float*)d_in[5];
    const float* sw  = (const float*)d_in[6];
    const float* sb  = (const float*)d_in[7];
    const float* rsw = (const float*)d_in[8];
    const float* rsb = (const float*)d_in[9];
    const float* cw  = (const float*)d_in[10];
    const float* cb  = (const float*)d_in[11];
    const float* ow  = (const float*)d_in[12];
    const float* ob  = (const float*)d_in[13];
    float* out  = (float*)d_out;
    float* dist = out + (size_t)BB * TT * OUTW;

    auto planSize = [&](int tch) -> size_t {
        size_t o = 0;
        auto al = [&](size_t bytes) { o += (bytes + 255) & ~(size_t)255; };
        int ring = tch + 9;
        al((size_t)ring * BH2 * 2);            // hRing (hi|lo)
        al((size_t)BB * HH * 4);               // cSt
        al((size_t)4096 * 1024 * 2);           // WhiP
        al((size_t)4096 * 1024 * 2);           // WloP
        al((size_t)32 * 1024 * 2);             // WspT
        al((size_t)NPAD * KXP * 2);            // WxT
        al((size_t)NPAD * 4);                  // bcp
        al((size_t)tch * 256 * NPAD * 4);      // xoX
        al((size_t)tch * 256 * KXP * 2);       // XAc
        al((size_t)TT * 256 * 16 * 4);         // fmAll (global-t indexed)
        al((size_t)tch * 256 * CSW * 4);       // ldC
        al((size_t)HH * HH * CSW * 2);         // ctT
        al((size_t)256 * 1024 * 2);            // swT
        al((size_t)256 * 4);                   // sbP
        al((size_t)1024 * 256 * 2);            // rswT
        al((size_t)OUTW * HH * 2);             // owT
        al((size_t)tch * 256 * HH * 2);        // MLH / RNN
        al((size_t)tch * 256 * 256 * 2);       // TH1
        al((size_t)tch * 256 * HH * 2);        // TH
        al(FLAGS_U32 * 4);                     // flags (global-t indexed)
        return o;
    };
    const int cands[4] = {16, 8, 4, 2};
    int TCH = 0;
    for (int ci = 0; ci < 4; ++ci)
        if (planSize(cands[ci]) <= ws_size) { TCH = cands[ci]; break; }
    if (TCH == 0) return;   // diagnostic: output stays zero -> absmax ~0.83
    const int RING = TCH + 9;
    const int Mloc = TCH * 256;
    const int nM = Mloc / 128;

    char* base = (char*)d_ws;
    size_t off = 0;
    auto alloc = [&](size_t bytes) { char* p = base + off; off += (bytes + 255) & ~(size_t)255; return p; };
    ushort* hRing = (ushort*)alloc((size_t)RING * BH2 * 2);
    float*  cSt   = (float*) alloc((size_t)BB * HH * 4);
    ushort* WhiP  = (ushort*)alloc((size_t)4096 * 1024 * 2);
    ushort* WloP  = (ushort*)alloc((size_t)4096 * 1024 * 2);
    ushort* WspT  = (ushort*)alloc((size_t)32 * 1024 * 2);
    ushort* WxT   = (ushort*)alloc((size_t)NPAD * KXP * 2);
    float*  bcp   = (float*) alloc((size_t)NPAD * 4);
    float*  xoX   = (float*) alloc((size_t)Mloc * NPAD * 4);
    ushort* XAc   = (ushort*)alloc((size_t)Mloc * KXP * 2);
    float*  fmAll = (float*) alloc((size_t)TT * 256 * 16 * 4);
    float*  ldC   = (float*) alloc((size_t)Mloc * CSW * 4);
    ushort* ctT   = (ushort*)alloc((size_t)HH * HH * CSW * 2);
    ushort* swT   = (ushort*)alloc((size_t)256 * 1024 * 2);
    float*  sbP   = (float*) alloc((size_t)256 * 4);
    ushort* rswT  = (ushort*)alloc((size_t)1024 * 256 * 2);
    ushort* owT   = (ushort*)alloc((size_t)OUTW * HH * 2);
    ushort* MLH   = (ushort*)alloc((size_t)Mloc * HH * 2);
    ushort* TH1   = (ushort*)alloc((size_t)Mloc * 256 * 2);
    ushort* TH    = (ushort*)alloc((size_t)Mloc * HH * 2);
    unsigned int* flags = (unsigned int*)alloc(FLAGS_U32 * 4);
    ushort* RNN   = MLH;

    hipMemsetAsync(hRing, 0, (size_t)9 * BH2 * 2, stream);
    hipMemsetAsync(cSt, 0, (size_t)BB * HH * 4, stream);
    hipMemsetAsync(flags, 0, FLAGS_U32 * 4, stream);

    build_whlP<<<(int)(((size_t)4096 * 1024 + 255) / 256), 256, 0, stream>>>(rw, WhiP, WloP);
    build_wsp<<<(16 * 1024 + 255) / 256, 256, 0, stream>>>(rw, WspT);
    build_wxt<<<(int)(((size_t)NPAD * KXP + 255) / 256), 256, 0, stream>>>(kw, rw, WxT);
    build_bcp<<<(NPAD + 255) / 256, 256, 0, stream>>>(kb, rb, bcp);
    build_ctt<<<(int)(((size_t)HH * HH * CSW + 255) / 256), 256, 0, stream>>>(cw, ctT);
    build_swt<<<(256 * 1024 + 255) / 256, 256, 0, stream>>>(sw, sb, swT, sbP);
    build_rswt<<<(1024 * 256 + 255) / 256, 256, 0, stream>>>(rsw, rswT);
    build_owt<<<(OUTW * HH + 255) / 256, 256, 0, stream>>>(ow, owT);

    for (int tBase = 0; tBase < TT; tBase += TCH) {
        // ---- batched x-part: xoX = XAc @ WxT (permuted N) ----
        build_xac<<<(int)(((size_t)Mloc * KXP + 255) / 256), 256, 0, stream>>>(
            x, tim, XAc, tBase, Mloc);
        mm_kernel<2, 2, 0, 0><<<dim3(33, Mloc / 128), 256, 0, stream>>>(
            XAc, nullptr, WxT, nullptr, xoX, nullptr, nullptr, nullptr,
            KXP, KXP, NPAD, KXP, 0, RING, tBase);
        // ---- persistent scan (RMW-only sync, depth-4 prefetch) ----
        scan_kernel<<<NBLK, 512, 0, stream>>>(
            WhiP, WloP, WspT, hRing, cSt, xoX, bcp, fmAll, dist, flags,
            tBase, TCH, RING);
        // ---- batched phase-2 ----
        ld_chunk_kernel<<<(Mloc + 255) / 256, 256, 0, stream>>>(dist, ldC, tBase, Mloc);
        mlh_kernel<<<Mloc / 2, 256, 0, stream>>>(hRing, ldC, MLH, tBase, RING);
        mm_kernel<2, 2, 0, 1><<<dim3(2, Mloc / 128), 256, 0, stream>>>(
            MLH, nullptr, swT, sbP, TH1, nullptr, nullptr, nullptr,
            1024, 1024, 256, 1024, 0, RING, tBase);
        mm_kernel<2, 2, 0, 2><<<dim3(8, Mloc / 128), 256, 0, stream>>>(
            TH1, nullptr, rswT, rsb, TH, nullptr, nullptr, nullptr,
            256, 256, 1024, 256, 0, RING, tBase);
        mm_kernel<2, 2, 2, 3><<<dim3(((nM + 7) / 8) * 64), 256, 0, stream>>>(
            nullptr, hRing, ctT, cb, RNN, ldC, TH, nullptr,
            0, HH * CSW, 1024, HH * CSW, nM, RING, tBase);
        mm_kernel<4, 1, 0, 4><<<dim3(1, Mloc / 256), 256, 0, stream>>>(
            RNN, nullptr, owT, ob, nullptr, nullptr, nullptr, out,
            1024, 1024, 0, 1024, 0, RING, tBase);
    }
}